// Round 1
// baseline (1201.358 us; speedup 1.0000x reference)
//
#include <hip/hip_runtime.h>
#include <hip/hip_bf16.h>

#define EPS 1e-5f

// ---------------------------------------------------------------- fold bn
__global__ __launch_bounds__(256) void fold_k(
    const float* __restrict__ w1, const float* __restrict__ g1, const float* __restrict__ b1,
    const float* __restrict__ m1, const float* __restrict__ v1,
    const float* __restrict__ g2, const float* __restrict__ b2,
    const float* __restrict__ m2, const float* __restrict__ v2,
    const float* __restrict__ w2, const float* __restrict__ g3, const float* __restrict__ b3,
    const float* __restrict__ m3, const float* __restrict__ v3,
    float* __restrict__ w1f, float* __restrict__ bias1,
    float* __restrict__ w2f, float* __restrict__ bias3,
    float* __restrict__ s2, float* __restrict__ t2) {
  int i = blockIdx.x * 256 + threadIdx.x;
  if (i < 384 * 64) {
    int o = i >> 6;
    float inv = g1[o] / sqrtf(v1[o] + EPS);
    w1f[i] = w1[i] * inv;
  }
  if (i < 384) {
    float inv = g1[i] / sqrtf(v1[i] + EPS);
    bias1[i] = b1[i] - m1[i] * inv;
    float inv2 = g2[i] / sqrtf(v2[i] + EPS);
    s2[i] = inv2;
    t2[i] = b2[i] - m2[i] * inv2;
  }
  if (i < 128 * 384) {
    int o = i / 384;
    float inv = g3[o] / sqrtf(v3[o] + EPS);
    w2f[i] = w2[i] * inv;
  }
  if (i < 128) {
    float inv = g3[i] / sqrtf(v3[i] + EPS);
    bias3[i] = b3[i] - m3[i] * inv;
  }
}

// ---------------------------------------------------------------- 1x1 conv (GEMM)
// out[b][oc][p] = act( sum_ic wf[oc][ic] * in[b][ic][p] + bias[oc] )
// grid: (npx/64, OC/64, B). 256 threads, 4x4 micro-tile per thread.
template <int IC, int ACT>  // ACT: 0 none, 1 relu6
__global__ __launch_bounds__(256) void conv1x1_k(
    const float* __restrict__ in, const float* __restrict__ wf,
    const float* __restrict__ bias, float* __restrict__ out, int npx) {
  __shared__ float xs[64][64];  // [ic][px]
  __shared__ float wt[64][64];  // [ic][oc] (transposed)
  const int t = threadIdx.x;
  const int px_id = t & 15;
  const int oc_id = t >> 4;
  const int p0 = blockIdx.x * 64;
  const int oc0 = blockIdx.y * 64;
  const int b = blockIdx.z;
  const int OCT = gridDim.y * 64;
  const float* inb = in + (size_t)b * IC * npx;

  float acc[4][4] = {};

  for (int kc = 0; kc < IC; kc += 64) {
    // load x tile: 1024 float4
#pragma unroll
    for (int r = 0; r < 4; ++r) {
      int s = t + 256 * r;
      int ic = s >> 4, c4 = s & 15;
      *(float4*)&xs[ic][c4 * 4] =
          *(const float4*)&inb[(size_t)(kc + ic) * npx + p0 + c4 * 4];
    }
    // load w tile transposed
#pragma unroll
    for (int r = 0; r < 4; ++r) {
      int s = t + 256 * r;
      int oc = s >> 4, ic4 = s & 15;
      float4 wv = *(const float4*)&wf[(size_t)(oc0 + oc) * IC + kc + ic4 * 4];
      wt[ic4 * 4 + 0][oc] = wv.x;
      wt[ic4 * 4 + 1][oc] = wv.y;
      wt[ic4 * 4 + 2][oc] = wv.z;
      wt[ic4 * 4 + 3][oc] = wv.w;
    }
    __syncthreads();
#pragma unroll
    for (int ic = 0; ic < 64; ++ic) {
      float4 xv = *(const float4*)&xs[ic][px_id * 4];
      float4 wv = *(const float4*)&wt[ic][oc_id * 4];
      acc[0][0] = fmaf(wv.x, xv.x, acc[0][0]);
      acc[0][1] = fmaf(wv.x, xv.y, acc[0][1]);
      acc[0][2] = fmaf(wv.x, xv.z, acc[0][2]);
      acc[0][3] = fmaf(wv.x, xv.w, acc[0][3]);
      acc[1][0] = fmaf(wv.y, xv.x, acc[1][0]);
      acc[1][1] = fmaf(wv.y, xv.y, acc[1][1]);
      acc[1][2] = fmaf(wv.y, xv.z, acc[1][2]);
      acc[1][3] = fmaf(wv.y, xv.w, acc[1][3]);
      acc[2][0] = fmaf(wv.z, xv.x, acc[2][0]);
      acc[2][1] = fmaf(wv.z, xv.y, acc[2][1]);
      acc[2][2] = fmaf(wv.z, xv.z, acc[2][2]);
      acc[2][3] = fmaf(wv.z, xv.w, acc[2][3]);
      acc[3][0] = fmaf(wv.w, xv.x, acc[3][0]);
      acc[3][1] = fmaf(wv.w, xv.y, acc[3][1]);
      acc[3][2] = fmaf(wv.w, xv.z, acc[3][2]);
      acc[3][3] = fmaf(wv.w, xv.w, acc[3][3]);
    }
    __syncthreads();
  }

#pragma unroll
  for (int i = 0; i < 4; ++i) {
    int oc = oc0 + oc_id * 4 + i;
    float bz = bias[oc];
    float4 o4;
    o4.x = acc[i][0] + bz;
    o4.y = acc[i][1] + bz;
    o4.z = acc[i][2] + bz;
    o4.w = acc[i][3] + bz;
    if (ACT == 1) {
      o4.x = fminf(fmaxf(o4.x, 0.f), 6.f);
      o4.y = fminf(fmaxf(o4.y, 0.f), 6.f);
      o4.z = fminf(fmaxf(o4.z, 0.f), 6.f);
      o4.w = fminf(fmaxf(o4.w, 0.f), 6.f);
    }
    *(float4*)&out[((size_t)b * OCT + oc) * npx + p0 + px_id * 4] = o4;
  }
}

// ---------------------------------------------------------------- mask conv 5x5 s2
// logits[b][k][ho][wo] = sum_{cm,di,dj} y[b][cm][2ho+di-2][2wo+dj-2]*we[k][cm][di][dj] + be[k]
__global__ __launch_bounds__(256) void mask_conv_k(
    const float* __restrict__ y, const float* __restrict__ we,
    const float* __restrict__ be, float* __restrict__ logits) {
  const int k = blockIdx.y, b = blockIdx.z;
  __shared__ float ws[64 * 25];
  for (int i = threadIdx.x; i < 1600; i += 256) ws[i] = we[(size_t)k * 1600 + i];
  __syncthreads();
  int sp = blockIdx.x * 256 + threadIdx.x;
  if (sp >= 3136) return;
  int ho = sp / 56, wo = sp % 56;
  const float* yb = y + (size_t)b * 64 * 12544;
  float acc = be[k];
  for (int cm = 0; cm < 64; ++cm) {
    const float* yc = yb + (size_t)cm * 12544;
    const float* wc_ = &ws[cm * 25];
#pragma unroll
    for (int di = 0; di < 5; ++di) {
      int hi = 2 * ho + di - 2;
      if (hi < 0 || hi >= 112) continue;
      const float* yr = yc + hi * 112;
#pragma unroll
      for (int dj = 0; dj < 5; ++dj) {
        int wi = 2 * wo + dj - 2;
        if (wi < 0 || wi >= 112) continue;
        acc = fmaf(yr[wi], wc_[di * 5 + dj], acc);
      }
    }
  }
  logits[((size_t)b * 25 + k) * 3136 + sp] = acc;
}

// ---------------------------------------------------------------- softmax over k=25 (in place)
__global__ __launch_bounds__(256) void softmax_k(float* __restrict__ m) {
  int idx = blockIdx.x * 256 + threadIdx.x;
  if (idx >= 8 * 3136) return;
  int b = idx / 3136, sp = idx % 3136;
  float* L = m + (size_t)b * 25 * 3136 + sp;
  float v[25];
  float mx = -1e30f;
#pragma unroll
  for (int k = 0; k < 25; ++k) {
    v[k] = L[(size_t)k * 3136];
    mx = fmaxf(mx, v[k]);
  }
  float s = 0.f;
#pragma unroll
  for (int k = 0; k < 25; ++k) {
    v[k] = __expf(v[k] - mx);
    s += v[k];
  }
  float inv = 1.0f / s;
#pragma unroll
  for (int k = 0; k < 25; ++k) L[(size_t)k * 3136] = v[k] * inv;
}

// ---------------------------------------------------------------- carafe + bn2 + relu6
__global__ __launch_bounds__(256) void carafe_k(
    const float* __restrict__ h, const float* __restrict__ msk,
    const float* __restrict__ s2, const float* __restrict__ t2,
    float* __restrict__ h2) {
  const int total = 8 * 384 * 56 * 56;
  for (int idx = blockIdx.x * 256 + threadIdx.x; idx < total;
       idx += gridDim.x * 256) {
    int wo = idx % 56;
    int tmp = idx / 56;
    int ho = tmp % 56;
    int c = (tmp / 56) % 384;
    int b = tmp / (56 * 384);
    const float* hp = h + ((size_t)b * 384 + c) * 12544;
    const float* mp = msk + (size_t)b * 25 * 3136 + ho * 56 + wo;
    float acc = 0.f;
#pragma unroll
    for (int i = 0; i < 5; ++i) {
      int hi = 2 * ho + i - 2;
      if (hi < 0 || hi >= 112) continue;
      const float* hr = hp + hi * 112;
#pragma unroll
      for (int j = 0; j < 5; ++j) {
        int wi = 2 * wo + j - 2;
        if (wi < 0 || wi >= 112) continue;
        acc = fmaf(hr[wi], mp[(size_t)(i * 5 + j) * 3136], acc);
      }
    }
    float r = s2[c] * acc + t2[c];
    h2[idx] = fminf(fmaxf(r, 0.f), 6.f);
  }
}

// ---------------------------------------------------------------- launch
extern "C" void kernel_launch(void* const* d_in, const int* in_sizes, int n_in,
                              void* d_out, int out_size, void* d_ws, size_t ws_size,
                              hipStream_t stream) {
  const float* x  = (const float*)d_in[0];
  const float* w1 = (const float*)d_in[1];
  const float* g1 = (const float*)d_in[2];
  const float* b1 = (const float*)d_in[3];
  const float* m1 = (const float*)d_in[4];
  const float* v1 = (const float*)d_in[5];
  const float* wc = (const float*)d_in[6];
  const float* bc = (const float*)d_in[7];
  const float* we = (const float*)d_in[8];
  const float* be = (const float*)d_in[9];
  const float* g2 = (const float*)d_in[10];
  const float* b2 = (const float*)d_in[11];
  const float* m2 = (const float*)d_in[12];
  const float* v2 = (const float*)d_in[13];
  const float* w2 = (const float*)d_in[14];
  const float* g3 = (const float*)d_in[15];
  const float* b3 = (const float*)d_in[16];
  const float* m3 = (const float*)d_in[17];
  const float* v3 = (const float*)d_in[18];
  float* out = (float*)d_out;

  float* ws = (float*)d_ws;
  float* h     = ws;                     // 8*384*112*112 = 38,535,168
  float* y     = h + 38535168;           // 8*64*112*112  =  6,422,528
  float* msk   = y + 6422528;            // 8*25*56*56    =    627,200
  float* h2    = msk + 627200;           // 8*384*56*56   =  9,633,792
  float* w1f   = h2 + 9633792;           // 24576
  float* bias1 = w1f + 24576;            // 384
  float* w2f   = bias1 + 384;            // 49152
  float* bias3 = w2f + 49152;            // 128
  float* s2    = bias3 + 128;            // 384
  float* t2    = s2 + 384;               // 384

  fold_k<<<192, 256, 0, stream>>>(w1, g1, b1, m1, v1, g2, b2, m2, v2,
                                  w2, g3, b3, m3, v3,
                                  w1f, bias1, w2f, bias3, s2, t2);

  // stage 1: h = relu6(bn1(conv1x1(x, w1)))
  conv1x1_k<64, 1><<<dim3(196, 6, 8), 256, 0, stream>>>(x, w1f, bias1, h, 12544);

  // compressor: y = conv1x1(h, wc) + bc
  conv1x1_k<384, 0><<<dim3(196, 1, 8), 256, 0, stream>>>(h, wc, bc, y, 12544);

  // mask conv + softmax
  mask_conv_k<<<dim3(13, 25, 8), 256, 0, stream>>>(y, we, be, msk);
  softmax_k<<<98, 256, 0, stream>>>(msk);

  // carafe + bn2 + relu6
  carafe_k<<<2048, 256, 0, stream>>>(h, msk, s2, t2, h2);

  // final: out = bn3(conv1x1(h2, w2))
  conv1x1_k<384, 0><<<dim3(49, 2, 8), 256, 0, stream>>>(h2, w2f, bias3, out, 3136);
}

// Round 2
// 579.769 us; speedup vs baseline: 2.0721x; 2.0721x over previous
//
#include <hip/hip_runtime.h>
#include <hip/hip_bf16.h>

#define EPS 1e-5f

// ---------------------------------------------------------------- fold bn
__global__ __launch_bounds__(256) void fold_k(
    const float* __restrict__ w1, const float* __restrict__ g1, const float* __restrict__ b1,
    const float* __restrict__ m1, const float* __restrict__ v1,
    const float* __restrict__ g2, const float* __restrict__ b2,
    const float* __restrict__ m2, const float* __restrict__ v2,
    const float* __restrict__ w2, const float* __restrict__ g3, const float* __restrict__ b3,
    const float* __restrict__ m3, const float* __restrict__ v3,
    float* __restrict__ w1f, float* __restrict__ bias1,
    float* __restrict__ w2f, float* __restrict__ bias3,
    float* __restrict__ s2, float* __restrict__ t2) {
  int i = blockIdx.x * 256 + threadIdx.x;
  if (i < 384 * 64) {
    int o = i >> 6;
    float inv = g1[o] / sqrtf(v1[o] + EPS);
    w1f[i] = w1[i] * inv;
  }
  if (i < 384) {
    float inv = g1[i] / sqrtf(v1[i] + EPS);
    bias1[i] = b1[i] - m1[i] * inv;
    float inv2 = g2[i] / sqrtf(v2[i] + EPS);
    s2[i] = inv2;
    t2[i] = b2[i] - m2[i] * inv2;
  }
  if (i < 128 * 384) {
    int o = i / 384;
    float inv = g3[o] / sqrtf(v3[o] + EPS);
    w2f[i] = w2[i] * inv;
  }
  if (i < 128) {
    float inv = g3[i] / sqrtf(v3[i] + EPS);
    bias3[i] = b3[i] - m3[i] * inv;
  }
}

// ---------------------------------------------------------------- transpose mask weights
// we[k][cm][tap] (25,64,25) -> wl[cm][tap][k] (64,25,25): k contiguous for s_load
__global__ __launch_bounds__(256) void wtrans_k(const float* __restrict__ we,
                                               float* __restrict__ wl) {
  int i = blockIdx.x * 256 + threadIdx.x;
  if (i >= 40000) return;
  int k = i / 1600;
  int rem = i - k * 1600;
  int cm = rem / 25;
  int tap = rem - cm * 25;
  wl[(cm * 25 + tap) * 25 + k] = we[i];
}

// ---------------------------------------------------------------- 1x1 conv (GEMM)
template <int IC, int ACT>  // ACT: 0 none, 1 relu6
__global__ __launch_bounds__(256) void conv1x1_k(
    const float* __restrict__ in, const float* __restrict__ wf,
    const float* __restrict__ bias, float* __restrict__ out, int npx) {
  __shared__ float xs[64][64];  // [ic][px]
  __shared__ float wt[64][64];  // [ic][oc] (transposed)
  const int t = threadIdx.x;
  const int px_id = t & 15;
  const int oc_id = t >> 4;
  const int p0 = blockIdx.x * 64;
  const int oc0 = blockIdx.y * 64;
  const int b = blockIdx.z;
  const int OCT = gridDim.y * 64;
  const float* inb = in + (size_t)b * IC * npx;

  float acc[4][4] = {};

  for (int kc = 0; kc < IC; kc += 64) {
#pragma unroll
    for (int r = 0; r < 4; ++r) {
      int s = t + 256 * r;
      int ic = s >> 4, c4 = s & 15;
      *(float4*)&xs[ic][c4 * 4] =
          *(const float4*)&inb[(size_t)(kc + ic) * npx + p0 + c4 * 4];
    }
#pragma unroll
    for (int r = 0; r < 4; ++r) {
      int s = t + 256 * r;
      int oc = s >> 4, ic4 = s & 15;
      float4 wv = *(const float4*)&wf[(size_t)(oc0 + oc) * IC + kc + ic4 * 4];
      wt[ic4 * 4 + 0][oc] = wv.x;
      wt[ic4 * 4 + 1][oc] = wv.y;
      wt[ic4 * 4 + 2][oc] = wv.z;
      wt[ic4 * 4 + 3][oc] = wv.w;
    }
    __syncthreads();
#pragma unroll
    for (int ic = 0; ic < 64; ++ic) {
      float4 xv = *(const float4*)&xs[ic][px_id * 4];
      float4 wv = *(const float4*)&wt[ic][oc_id * 4];
      acc[0][0] = fmaf(wv.x, xv.x, acc[0][0]);
      acc[0][1] = fmaf(wv.x, xv.y, acc[0][1]);
      acc[0][2] = fmaf(wv.x, xv.z, acc[0][2]);
      acc[0][3] = fmaf(wv.x, xv.w, acc[0][3]);
      acc[1][0] = fmaf(wv.y, xv.x, acc[1][0]);
      acc[1][1] = fmaf(wv.y, xv.y, acc[1][1]);
      acc[1][2] = fmaf(wv.y, xv.z, acc[1][2]);
      acc[1][3] = fmaf(wv.y, xv.w, acc[1][3]);
      acc[2][0] = fmaf(wv.z, xv.x, acc[2][0]);
      acc[2][1] = fmaf(wv.z, xv.y, acc[2][1]);
      acc[2][2] = fmaf(wv.z, xv.z, acc[2][2]);
      acc[2][3] = fmaf(wv.z, xv.w, acc[2][3]);
      acc[3][0] = fmaf(wv.w, xv.x, acc[3][0]);
      acc[3][1] = fmaf(wv.w, xv.y, acc[3][1]);
      acc[3][2] = fmaf(wv.w, xv.z, acc[3][2]);
      acc[3][3] = fmaf(wv.w, xv.w, acc[3][3]);
    }
    __syncthreads();
  }

#pragma unroll
  for (int i = 0; i < 4; ++i) {
    int oc = oc0 + oc_id * 4 + i;
    float bz = bias[oc];
    float4 o4;
    o4.x = acc[i][0] + bz;
    o4.y = acc[i][1] + bz;
    o4.z = acc[i][2] + bz;
    o4.w = acc[i][3] + bz;
    if (ACT == 1) {
      o4.x = fminf(fmaxf(o4.x, 0.f), 6.f);
      o4.y = fminf(fmaxf(o4.y, 0.f), 6.f);
      o4.z = fminf(fmaxf(o4.z, 0.f), 6.f);
      o4.w = fminf(fmaxf(o4.w, 0.f), 6.f);
    }
    *(float4*)&out[((size_t)b * OCT + oc) * npx + p0 + px_id * 4] = o4;
  }
}

// ---------------------------------------------------------------- mask conv 5x5 s2 (v2)
// Tile: 8 output rows x 56 cols per block; cm split by 4 across blockIdx.z.
// LDS-staged y patch (4 ch chunks), weights via wave-uniform (scalar) loads.
// mpart[z][b][k][sp] partial logits (no bias).
__global__ __launch_bounds__(512) void mask_conv2_k(
    const float* __restrict__ y, const float* __restrict__ wl,
    float* __restrict__ mpart) {
  __shared__ float ys[4][19][120];
  const int hx = blockIdx.x;  // 0..6
  const int b = blockIdx.y;   // 0..7
  const int z = blockIdx.z;   // 0..3
  const int ho0 = hx * 8;
  const int tid = threadIdx.x;
  const int r = tid / 56, c = tid - (tid / 56) * 56;  // valid for tid<448

  float acc[25];
#pragma unroll
  for (int k = 0; k < 25; ++k) acc[k] = 0.f;

  for (int c4 = 0; c4 < 4; ++c4) {
    const int cmbase = z * 16 + c4 * 4;
    __syncthreads();
    // stage 4 channels x 19 rows x 116 cols (zero-padded)
    for (int i = tid; i < 4 * 19 * 116; i += 512) {
      int ch = i / 2204;
      int rem = i - ch * 2204;
      int rr = rem / 116;
      int wcol = rem - rr * 116;
      int hi = ho0 * 2 - 2 + rr;
      int wi = wcol - 2;
      float v = 0.f;
      if ((unsigned)hi < 112u && (unsigned)wi < 112u)
        v = y[((size_t)(b * 64 + cmbase + ch) * 112 + hi) * 112 + wi];
      ys[ch][rr][wcol] = v;
    }
    __syncthreads();
    if (tid < 448) {
#pragma unroll
      for (int cml = 0; cml < 4; ++cml) {
        float p[25];
#pragma unroll
        for (int di = 0; di < 5; ++di)
#pragma unroll
          for (int dj = 0; dj < 5; ++dj)
            p[di * 5 + dj] = ys[cml][2 * r + di][2 * c + dj];
        const float* __restrict__ wb = wl + (size_t)(cmbase + cml) * 625;
#pragma unroll
        for (int tap = 0; tap < 25; ++tap) {
          float pv = p[tap];
#pragma unroll
          for (int k = 0; k < 25; ++k)
            acc[k] = fmaf(wb[tap * 25 + k], pv, acc[k]);
        }
      }
    }
  }
  if (tid < 448) {
    int sp = (ho0 + r) * 56 + c;
#pragma unroll
    for (int k = 0; k < 25; ++k)
      mpart[((size_t)(z * 8 + b) * 25 + k) * 3136 + sp] = acc[k];
  }
}

// ---------------------------------------------------------------- softmax (combine 4 partials + bias)
__global__ __launch_bounds__(256) void softmax2_k(
    const float* __restrict__ mpart, const float* __restrict__ be,
    float* __restrict__ msk) {
  int idx = blockIdx.x * 256 + threadIdx.x;
  if (idx >= 8 * 3136) return;
  int b = idx / 3136, sp = idx - (idx / 3136) * 3136;
  float v[25];
  float mx = -1e30f;
#pragma unroll
  for (int k = 0; k < 25; ++k) {
    size_t o = ((size_t)b * 25 + k) * 3136 + sp;
    float s = mpart[o] + mpart[627200 + o] + mpart[2 * 627200 + o] +
              mpart[3 * 627200 + o] + be[k];
    v[k] = s;
    mx = fmaxf(mx, s);
  }
  float s = 0.f;
#pragma unroll
  for (int k = 0; k < 25; ++k) {
    v[k] = __expf(v[k] - mx);
    s += v[k];
  }
  float inv = 1.0f / s;
#pragma unroll
  for (int k = 0; k < 25; ++k)
    msk[((size_t)b * 25 + k) * 3136 + sp] = v[k] * inv;
}

// ---------------------------------------------------------------- carafe + bn2 + relu6
__global__ __launch_bounds__(256) void carafe_k(
    const float* __restrict__ h, const float* __restrict__ msk,
    const float* __restrict__ s2, const float* __restrict__ t2,
    float* __restrict__ h2) {
  const int total = 8 * 384 * 56 * 56;
  for (int idx = blockIdx.x * 256 + threadIdx.x; idx < total;
       idx += gridDim.x * 256) {
    int wo = idx % 56;
    int tmp = idx / 56;
    int ho = tmp % 56;
    int c = (tmp / 56) % 384;
    int b = tmp / (56 * 384);
    const float* hp = h + ((size_t)b * 384 + c) * 12544;
    const float* mp = msk + (size_t)b * 25 * 3136 + ho * 56 + wo;
    float acc = 0.f;
#pragma unroll
    for (int i = 0; i < 5; ++i) {
      int hi = 2 * ho + i - 2;
      if (hi < 0 || hi >= 112) continue;
      const float* hr = hp + hi * 112;
#pragma unroll
      for (int j = 0; j < 5; ++j) {
        int wi = 2 * wo + j - 2;
        if (wi < 0 || wi >= 112) continue;
        acc = fmaf(hr[wi], mp[(size_t)(i * 5 + j) * 3136], acc);
      }
    }
    float r = s2[c] * acc + t2[c];
    h2[idx] = fminf(fmaxf(r, 0.f), 6.f);
  }
}

// ---------------------------------------------------------------- launch
extern "C" void kernel_launch(void* const* d_in, const int* in_sizes, int n_in,
                              void* d_out, int out_size, void* d_ws, size_t ws_size,
                              hipStream_t stream) {
  const float* x  = (const float*)d_in[0];
  const float* w1 = (const float*)d_in[1];
  const float* g1 = (const float*)d_in[2];
  const float* b1 = (const float*)d_in[3];
  const float* m1 = (const float*)d_in[4];
  const float* v1 = (const float*)d_in[5];
  const float* wc = (const float*)d_in[6];
  const float* bc = (const float*)d_in[7];
  const float* we = (const float*)d_in[8];
  const float* be = (const float*)d_in[9];
  const float* g2 = (const float*)d_in[10];
  const float* b2 = (const float*)d_in[11];
  const float* m2 = (const float*)d_in[12];
  const float* v2 = (const float*)d_in[13];
  const float* w2 = (const float*)d_in[14];
  const float* g3 = (const float*)d_in[15];
  const float* b3 = (const float*)d_in[16];
  const float* m3 = (const float*)d_in[17];
  const float* v3 = (const float*)d_in[18];
  float* out = (float*)d_out;

  float* ws = (float*)d_ws;
  float* h     = ws;                     // 38,535,168
  float* y     = h + 38535168;           //  6,422,528 (mask final aliases here)
  float* h2    = y + 6422528;            //  9,633,792 (mask partials alias here)
  float* w1f   = h2 + 9633792;           // 24576
  float* bias1 = w1f + 24576;            // 384
  float* w2f   = bias1 + 384;            // 49152
  float* bias3 = w2f + 49152;            // 128
  float* s2    = bias3 + 128;            // 384
  float* t2    = s2 + 384;               // 384
  float* wl    = t2 + 384;               // 40000
  float* mpart = h2;                     // 4*627,200 = 2,508,800 (alias, consumed before carafe)
  float* mskf  = y;                      // 627,200 (alias, y consumed before softmax writes)

  fold_k<<<192, 256, 0, stream>>>(w1, g1, b1, m1, v1, g2, b2, m2, v2,
                                  w2, g3, b3, m3, v3,
                                  w1f, bias1, w2f, bias3, s2, t2);
  wtrans_k<<<157, 256, 0, stream>>>(we, wl);

  // stage 1: h = relu6(bn1(conv1x1(x, w1)))
  conv1x1_k<64, 1><<<dim3(196, 6, 8), 256, 0, stream>>>(x, w1f, bias1, h, 12544);

  // compressor: y = conv1x1(h, wc) + bc
  conv1x1_k<384, 0><<<dim3(196, 1, 8), 256, 0, stream>>>(h, wc, bc, y, 12544);

  // mask conv (partials) + softmax (combine + bias)
  mask_conv2_k<<<dim3(7, 8, 4), 512, 0, stream>>>(y, wl, mpart);
  softmax2_k<<<98, 256, 0, stream>>>(mpart, be, mskf);

  // carafe + bn2 + relu6 (overwrites mpart region after it is consumed)
  carafe_k<<<2048, 256, 0, stream>>>(h, mskf, s2, t2, h2);

  // final: out = bn3(conv1x1(h2, w2))
  conv1x1_k<384, 0><<<dim3(49, 2, 8), 256, 0, stream>>>(h2, w2f, bias3, out, 3136);
}

// Round 3
// 468.731 us; speedup vs baseline: 2.5630x; 1.2369x over previous
//
#include <hip/hip_runtime.h>
#include <hip/hip_bf16.h>

#define EPS 1e-5f

// ---------------------------------------------------------------- fold bn
__global__ __launch_bounds__(256) void fold_k(
    const float* __restrict__ w1, const float* __restrict__ g1, const float* __restrict__ b1,
    const float* __restrict__ m1, const float* __restrict__ v1,
    const float* __restrict__ g2, const float* __restrict__ b2,
    const float* __restrict__ m2, const float* __restrict__ v2,
    const float* __restrict__ w2, const float* __restrict__ g3, const float* __restrict__ b3,
    const float* __restrict__ m3, const float* __restrict__ v3,
    float* __restrict__ w1f, float* __restrict__ bias1,
    float* __restrict__ w2f, float* __restrict__ bias3,
    float* __restrict__ s2, float* __restrict__ t2) {
  int i = blockIdx.x * 256 + threadIdx.x;
  if (i < 384 * 64) {
    int o = i >> 6;
    float inv = g1[o] / sqrtf(v1[o] + EPS);
    w1f[i] = w1[i] * inv;
  }
  if (i < 384) {
    float inv = g1[i] / sqrtf(v1[i] + EPS);
    bias1[i] = b1[i] - m1[i] * inv;
    float inv2 = g2[i] / sqrtf(v2[i] + EPS);
    s2[i] = inv2;
    t2[i] = b2[i] - m2[i] * inv2;
  }
  if (i < 128 * 384) {
    int o = i / 384;
    float inv = g3[o] / sqrtf(v3[o] + EPS);
    w2f[i] = w2[i] * inv;
  }
  if (i < 128) {
    float inv = g3[i] / sqrtf(v3[i] + EPS);
    bias3[i] = b3[i] - m3[i] * inv;
  }
}

// ---------------------------------------------------------------- transpose mask weights
__global__ __launch_bounds__(256) void wtrans_k(const float* __restrict__ we,
                                               float* __restrict__ wl) {
  int i = blockIdx.x * 256 + threadIdx.x;
  if (i >= 40000) return;
  int k = i / 1600;
  int rem = i - k * 1600;
  int cm = rem / 25;
  int tap = rem - cm * 25;
  wl[(cm * 25 + tap) * 25 + k] = we[i];
}

// ---------------------------------------------------------------- 1x1 conv (GEMM)
template <int IC, int ACT>
__global__ __launch_bounds__(256) void conv1x1_k(
    const float* __restrict__ in, const float* __restrict__ wf,
    const float* __restrict__ bias, float* __restrict__ out, int npx) {
  __shared__ float xs[64][64];
  __shared__ float wt[64][64];
  const int t = threadIdx.x;
  const int px_id = t & 15;
  const int oc_id = t >> 4;
  const int p0 = blockIdx.x * 64;
  const int oc0 = blockIdx.y * 64;
  const int b = blockIdx.z;
  const int OCT = gridDim.y * 64;
  const float* inb = in + (size_t)b * IC * npx;

  float acc[4][4] = {};

  for (int kc = 0; kc < IC; kc += 64) {
#pragma unroll
    for (int r = 0; r < 4; ++r) {
      int s = t + 256 * r;
      int ic = s >> 4, c4 = s & 15;
      *(float4*)&xs[ic][c4 * 4] =
          *(const float4*)&inb[(size_t)(kc + ic) * npx + p0 + c4 * 4];
    }
#pragma unroll
    for (int r = 0; r < 4; ++r) {
      int s = t + 256 * r;
      int oc = s >> 4, ic4 = s & 15;
      float4 wv = *(const float4*)&wf[(size_t)(oc0 + oc) * IC + kc + ic4 * 4];
      wt[ic4 * 4 + 0][oc] = wv.x;
      wt[ic4 * 4 + 1][oc] = wv.y;
      wt[ic4 * 4 + 2][oc] = wv.z;
      wt[ic4 * 4 + 3][oc] = wv.w;
    }
    __syncthreads();
#pragma unroll
    for (int ic = 0; ic < 64; ++ic) {
      float4 xv = *(const float4*)&xs[ic][px_id * 4];
      float4 wv = *(const float4*)&wt[ic][oc_id * 4];
      acc[0][0] = fmaf(wv.x, xv.x, acc[0][0]);
      acc[0][1] = fmaf(wv.x, xv.y, acc[0][1]);
      acc[0][2] = fmaf(wv.x, xv.z, acc[0][2]);
      acc[0][3] = fmaf(wv.x, xv.w, acc[0][3]);
      acc[1][0] = fmaf(wv.y, xv.x, acc[1][0]);
      acc[1][1] = fmaf(wv.y, xv.y, acc[1][1]);
      acc[1][2] = fmaf(wv.y, xv.z, acc[1][2]);
      acc[1][3] = fmaf(wv.y, xv.w, acc[1][3]);
      acc[2][0] = fmaf(wv.z, xv.x, acc[2][0]);
      acc[2][1] = fmaf(wv.z, xv.y, acc[2][1]);
      acc[2][2] = fmaf(wv.z, xv.z, acc[2][2]);
      acc[2][3] = fmaf(wv.z, xv.w, acc[2][3]);
      acc[3][0] = fmaf(wv.w, xv.x, acc[3][0]);
      acc[3][1] = fmaf(wv.w, xv.y, acc[3][1]);
      acc[3][2] = fmaf(wv.w, xv.z, acc[3][2]);
      acc[3][3] = fmaf(wv.w, xv.w, acc[3][3]);
    }
    __syncthreads();
  }

#pragma unroll
  for (int i = 0; i < 4; ++i) {
    int oc = oc0 + oc_id * 4 + i;
    float bz = bias[oc];
    float4 o4;
    o4.x = acc[i][0] + bz;
    o4.y = acc[i][1] + bz;
    o4.z = acc[i][2] + bz;
    o4.w = acc[i][3] + bz;
    if (ACT == 1) {
      o4.x = fminf(fmaxf(o4.x, 0.f), 6.f);
      o4.y = fminf(fmaxf(o4.y, 0.f), 6.f);
      o4.z = fminf(fmaxf(o4.z, 0.f), 6.f);
      o4.w = fminf(fmaxf(o4.w, 0.f), 6.f);
    }
    *(float4*)&out[((size_t)b * OCT + oc) * npx + p0 + px_id * 4] = o4;
  }
}

// ---------------------------------------------------------------- mask conv 5x5 s2
__global__ __launch_bounds__(512) void mask_conv2_k(
    const float* __restrict__ y, const float* __restrict__ wl,
    float* __restrict__ mpart) {
  __shared__ float ys[4][19][120];
  const int hx = blockIdx.x;
  const int b = blockIdx.y;
  const int z = blockIdx.z;
  const int ho0 = hx * 8;
  const int tid = threadIdx.x;
  const int r = tid / 56, c = tid - (tid / 56) * 56;

  float acc[25];
#pragma unroll
  for (int k = 0; k < 25; ++k) acc[k] = 0.f;

  for (int c4 = 0; c4 < 4; ++c4) {
    const int cmbase = z * 16 + c4 * 4;
    __syncthreads();
    for (int i = tid; i < 4 * 19 * 116; i += 512) {
      int ch = i / 2204;
      int rem = i - ch * 2204;
      int rr = rem / 116;
      int wcol = rem - rr * 116;
      int hi = ho0 * 2 - 2 + rr;
      int wi = wcol - 2;
      float v = 0.f;
      if ((unsigned)hi < 112u && (unsigned)wi < 112u)
        v = y[((size_t)(b * 64 + cmbase + ch) * 112 + hi) * 112 + wi];
      ys[ch][rr][wcol] = v;
    }
    __syncthreads();
    if (tid < 448) {
#pragma unroll
      for (int cml = 0; cml < 4; ++cml) {
        float p[25];
#pragma unroll
        for (int di = 0; di < 5; ++di)
#pragma unroll
          for (int dj = 0; dj < 5; ++dj)
            p[di * 5 + dj] = ys[cml][2 * r + di][2 * c + dj];
        const float* __restrict__ wb = wl + (size_t)(cmbase + cml) * 625;
#pragma unroll
        for (int tap = 0; tap < 25; ++tap) {
          float pv = p[tap];
#pragma unroll
          for (int k = 0; k < 25; ++k)
            acc[k] = fmaf(wb[tap * 25 + k], pv, acc[k]);
        }
      }
    }
  }
  if (tid < 448) {
    int sp = (ho0 + r) * 56 + c;
#pragma unroll
    for (int k = 0; k < 25; ++k)
      mpart[((size_t)(z * 8 + b) * 25 + k) * 3136 + sp] = acc[k];
  }
}

// ---------------------------------------------------------------- softmax
__global__ __launch_bounds__(256) void softmax2_k(
    const float* __restrict__ mpart, const float* __restrict__ be,
    float* __restrict__ msk) {
  int idx = blockIdx.x * 256 + threadIdx.x;
  if (idx >= 8 * 3136) return;
  int b = idx / 3136, sp = idx - (idx / 3136) * 3136;
  float v[25];
  float mx = -1e30f;
#pragma unroll
  for (int k = 0; k < 25; ++k) {
    size_t o = ((size_t)b * 25 + k) * 3136 + sp;
    float s = mpart[o] + mpart[627200 + o] + mpart[2 * 627200 + o] +
              mpart[3 * 627200 + o] + be[k];
    v[k] = s;
    mx = fmaxf(mx, s);
  }
  float s = 0.f;
#pragma unroll
  for (int k = 0; k < 25; ++k) {
    v[k] = __expf(v[k] - mx);
    s += v[k];
  }
  float inv = 1.0f / s;
#pragma unroll
  for (int k = 0; k < 25; ++k)
    msk[((size_t)b * 25 + k) * 3136 + sp] = v[k] * inv;
}

// ---------------------------------------------------------------- carafe v2
// Block = (8-row tile, batch, 48-channel chunk). Mask in registers (reused
// across all 48 channels); h slab staged per channel in padded LDS, double-
// buffered (one sync/channel). Fused bn2 + relu6.
__device__ __forceinline__ void stage_ch(float ysb[19][120],
                                         const float* __restrict__ hp,
                                         int ho0, int tid) {
  for (int i = tid; i < 532; i += 512) {
    int rr = i / 28;
    int c4 = (i - rr * 28) * 4;
    int hi = 2 * ho0 - 2 + rr;
    float4 v = {0.f, 0.f, 0.f, 0.f};
    if ((unsigned)hi < 112u) v = *(const float4*)&hp[hi * 112 + c4];
    ysb[rr][2 + c4 + 0] = v.x;
    ysb[rr][2 + c4 + 1] = v.y;
    ysb[rr][2 + c4 + 2] = v.z;
    ysb[rr][2 + c4 + 3] = v.w;
  }
}

__global__ __launch_bounds__(512) void carafe2_k(
    const float* __restrict__ h, const float* __restrict__ msk,
    const float* __restrict__ s2, const float* __restrict__ t2,
    float* __restrict__ h2) {
  __shared__ float ys[2][19][120];
  const int hx = blockIdx.x;   // 0..6
  const int b  = blockIdx.y;   // 0..7
  const int cz = blockIdx.z;   // 0..7
  const int ho0 = hx * 8;
  const int tid = threadIdx.x;
  const int r = tid / 56;
  const int c = tid - r * 56;

  // zero the horizontal pads once (cols 0,1,114..119; both buffers)
  for (int i = tid; i < 2 * 19 * 8; i += 512) {
    int bufi = i / 152;
    int rem = i - bufi * 152;
    int rr = rem / 8;
    int p = rem - rr * 8;
    int col = (p < 2) ? p : (112 + p);
    ys[bufi][rr][col] = 0.f;
  }

  // mask -> registers (reused for all 48 channels)
  float m[25];
  if (tid < 448) {
    const float* mp = msk + (size_t)b * 25 * 3136 + (ho0 + r) * 56 + c;
#pragma unroll
    for (int k = 0; k < 25; ++k) m[k] = mp[(size_t)k * 3136];
  }
  __syncthreads();

  const int c0 = cz * 48;
  stage_ch(ys[0], h + ((size_t)(b * 384 + c0) * 112) * 112, ho0, tid);
  __syncthreads();

  for (int ch = 0; ch < 48; ++ch) {
    const int bf = ch & 1;
    const int cc = c0 + ch;
    if (ch + 1 < 48)
      stage_ch(ys[bf ^ 1], h + ((size_t)(b * 384 + cc + 1) * 112) * 112, ho0, tid);
    if (tid < 448) {
      float acc = 0.f;
#pragma unroll
      for (int di = 0; di < 5; ++di) {
        const float* row = &ys[bf][2 * r + di][2 * c];
        float2 a01 = *(const float2*)&row[0];
        float2 a23 = *(const float2*)&row[2];
        float a4 = row[4];
        acc = fmaf(a01.x, m[di * 5 + 0], acc);
        acc = fmaf(a01.y, m[di * 5 + 1], acc);
        acc = fmaf(a23.x, m[di * 5 + 2], acc);
        acc = fmaf(a23.y, m[di * 5 + 3], acc);
        acc = fmaf(a4,    m[di * 5 + 4], acc);
      }
      float o = s2[cc] * acc + t2[cc];
      h2[((size_t)(b * 384 + cc) * 56 + ho0 + r) * 56 + c] =
          fminf(fmaxf(o, 0.f), 6.f);
    }
    __syncthreads();
  }
}

// ---------------------------------------------------------------- launch
extern "C" void kernel_launch(void* const* d_in, const int* in_sizes, int n_in,
                              void* d_out, int out_size, void* d_ws, size_t ws_size,
                              hipStream_t stream) {
  const float* x  = (const float*)d_in[0];
  const float* w1 = (const float*)d_in[1];
  const float* g1 = (const float*)d_in[2];
  const float* b1 = (const float*)d_in[3];
  const float* m1 = (const float*)d_in[4];
  const float* v1 = (const float*)d_in[5];
  const float* wc = (const float*)d_in[6];
  const float* bc = (const float*)d_in[7];
  const float* we = (const float*)d_in[8];
  const float* be = (const float*)d_in[9];
  const float* g2 = (const float*)d_in[10];
  const float* b2 = (const float*)d_in[11];
  const float* m2 = (const float*)d_in[12];
  const float* v2 = (const float*)d_in[13];
  const float* w2 = (const float*)d_in[14];
  const float* g3 = (const float*)d_in[15];
  const float* b3 = (const float*)d_in[16];
  const float* m3 = (const float*)d_in[17];
  const float* v3 = (const float*)d_in[18];
  float* out = (float*)d_out;

  float* ws = (float*)d_ws;
  float* h     = ws;                     // 38,535,168
  float* y     = h + 38535168;           //  6,422,528 (mask final aliases here)
  float* h2    = y + 6422528;            //  9,633,792 (mask partials alias here)
  float* w1f   = h2 + 9633792;           // 24576
  float* bias1 = w1f + 24576;            // 384
  float* w2f   = bias1 + 384;            // 49152
  float* bias3 = w2f + 49152;            // 128
  float* s2    = bias3 + 128;            // 384
  float* t2    = s2 + 384;               // 384
  float* wl    = t2 + 384;               // 40000
  float* mpart = h2;                     // alias, consumed before carafe writes
  float* mskf  = y;                      // alias, y consumed before softmax writes

  fold_k<<<192, 256, 0, stream>>>(w1, g1, b1, m1, v1, g2, b2, m2, v2,
                                  w2, g3, b3, m3, v3,
                                  w1f, bias1, w2f, bias3, s2, t2);
  wtrans_k<<<157, 256, 0, stream>>>(we, wl);

  conv1x1_k<64, 1><<<dim3(196, 6, 8), 256, 0, stream>>>(x, w1f, bias1, h, 12544);
  conv1x1_k<384, 0><<<dim3(196, 1, 8), 256, 0, stream>>>(h, wc, bc, y, 12544);

  mask_conv2_k<<<dim3(7, 8, 4), 512, 0, stream>>>(y, wl, mpart);
  softmax2_k<<<98, 256, 0, stream>>>(mpart, be, mskf);

  carafe2_k<<<dim3(7, 8, 8), 512, 0, stream>>>(h, mskf, s2, t2, h2);

  conv1x1_k<384, 0><<<dim3(49, 2, 8), 256, 0, stream>>>(h2, w2f, bias3, out, 3136);
}

// Round 4
// 425.286 us; speedup vs baseline: 2.8248x; 1.1022x over previous
//
#include <hip/hip_runtime.h>
#include <hip/hip_bf16.h>

#define EPS 1e-5f

// ---------------------------------------------------------------- fold bn
__global__ __launch_bounds__(256) void fold_k(
    const float* __restrict__ w1, const float* __restrict__ g1, const float* __restrict__ b1,
    const float* __restrict__ m1, const float* __restrict__ v1,
    const float* __restrict__ g2, const float* __restrict__ b2,
    const float* __restrict__ m2, const float* __restrict__ v2,
    const float* __restrict__ w2, const float* __restrict__ g3, const float* __restrict__ b3,
    const float* __restrict__ m3, const float* __restrict__ v3,
    float* __restrict__ w1f, float* __restrict__ bias1,
    float* __restrict__ w2f, float* __restrict__ bias3,
    float* __restrict__ s2, float* __restrict__ t2) {
  int i = blockIdx.x * 256 + threadIdx.x;
  if (i < 384 * 64) {
    int o = i >> 6;
    float inv = g1[o] / sqrtf(v1[o] + EPS);
    w1f[i] = w1[i] * inv;
  }
  if (i < 384) {
    float inv = g1[i] / sqrtf(v1[i] + EPS);
    bias1[i] = b1[i] - m1[i] * inv;
    float inv2 = g2[i] / sqrtf(v2[i] + EPS);
    s2[i] = inv2;
    t2[i] = b2[i] - m2[i] * inv2;
  }
  if (i < 128 * 384) {
    int o = i / 384;
    float inv = g3[o] / sqrtf(v3[o] + EPS);
    w2f[i] = w2[i] * inv;
  }
  if (i < 128) {
    float inv = g3[i] / sqrtf(v3[i] + EPS);
    bias3[i] = b3[i] - m3[i] * inv;
  }
}

// ---------------------------------------------------------------- transpose mask weights
__global__ __launch_bounds__(256) void wtrans_k(const float* __restrict__ we,
                                               float* __restrict__ wl) {
  int i = blockIdx.x * 256 + threadIdx.x;
  if (i >= 40000) return;
  int k = i / 1600;
  int rem = i - k * 1600;
  int cm = rem / 25;
  int tap = rem - cm * 25;
  wl[(cm * 25 + tap) * 25 + k] = we[i];
}

// ---------------------------------------------------------------- 1x1 conv (GEMM)
template <int IC, int ACT>
__global__ __launch_bounds__(256) void conv1x1_k(
    const float* __restrict__ in, const float* __restrict__ wf,
    const float* __restrict__ bias, float* __restrict__ out, int npx) {
  __shared__ float xs[64][64];
  __shared__ float wt[64][64];
  const int t = threadIdx.x;
  const int px_id = t & 15;
  const int oc_id = t >> 4;
  const int p0 = blockIdx.x * 64;
  const int oc0 = blockIdx.y * 64;
  const int b = blockIdx.z;
  const int OCT = gridDim.y * 64;
  const float* inb = in + (size_t)b * IC * npx;

  float acc[4][4] = {};

  for (int kc = 0; kc < IC; kc += 64) {
#pragma unroll
    for (int r = 0; r < 4; ++r) {
      int s = t + 256 * r;
      int ic = s >> 4, c4 = s & 15;
      *(float4*)&xs[ic][c4 * 4] =
          *(const float4*)&inb[(size_t)(kc + ic) * npx + p0 + c4 * 4];
    }
#pragma unroll
    for (int r = 0; r < 4; ++r) {
      int s = t + 256 * r;
      int oc = s >> 4, ic4 = s & 15;
      float4 wv = *(const float4*)&wf[(size_t)(oc0 + oc) * IC + kc + ic4 * 4];
      wt[ic4 * 4 + 0][oc] = wv.x;
      wt[ic4 * 4 + 1][oc] = wv.y;
      wt[ic4 * 4 + 2][oc] = wv.z;
      wt[ic4 * 4 + 3][oc] = wv.w;
    }
    __syncthreads();
#pragma unroll
    for (int ic = 0; ic < 64; ++ic) {
      float4 xv = *(const float4*)&xs[ic][px_id * 4];
      float4 wv = *(const float4*)&wt[ic][oc_id * 4];
      acc[0][0] = fmaf(wv.x, xv.x, acc[0][0]);
      acc[0][1] = fmaf(wv.x, xv.y, acc[0][1]);
      acc[0][2] = fmaf(wv.x, xv.z, acc[0][2]);
      acc[0][3] = fmaf(wv.x, xv.w, acc[0][3]);
      acc[1][0] = fmaf(wv.y, xv.x, acc[1][0]);
      acc[1][1] = fmaf(wv.y, xv.y, acc[1][1]);
      acc[1][2] = fmaf(wv.y, xv.z, acc[1][2]);
      acc[1][3] = fmaf(wv.y, xv.w, acc[1][3]);
      acc[2][0] = fmaf(wv.z, xv.x, acc[2][0]);
      acc[2][1] = fmaf(wv.z, xv.y, acc[2][1]);
      acc[2][2] = fmaf(wv.z, xv.z, acc[2][2]);
      acc[2][3] = fmaf(wv.z, xv.w, acc[2][3]);
      acc[3][0] = fmaf(wv.w, xv.x, acc[3][0]);
      acc[3][1] = fmaf(wv.w, xv.y, acc[3][1]);
      acc[3][2] = fmaf(wv.w, xv.z, acc[3][2]);
      acc[3][3] = fmaf(wv.w, xv.w, acc[3][3]);
    }
    __syncthreads();
  }

#pragma unroll
  for (int i = 0; i < 4; ++i) {
    int oc = oc0 + oc_id * 4 + i;
    float bz = bias[oc];
    float4 o4;
    o4.x = acc[i][0] + bz;
    o4.y = acc[i][1] + bz;
    o4.z = acc[i][2] + bz;
    o4.w = acc[i][3] + bz;
    if (ACT == 1) {
      o4.x = fminf(fmaxf(o4.x, 0.f), 6.f);
      o4.y = fminf(fmaxf(o4.y, 0.f), 6.f);
      o4.z = fminf(fmaxf(o4.z, 0.f), 6.f);
      o4.w = fminf(fmaxf(o4.w, 0.f), 6.f);
    }
    *(float4*)&out[((size_t)b * OCT + oc) * npx + p0 + px_id * 4] = o4;
  }
}

// ---------------------------------------------------------------- mask conv 5x5 s2 (v3)
// 4 output rows x 56 cols per block (224/256 threads); 8 channels per z-chunk
// staged 4 at a time. grid (14, 8, 8) = 896 blocks. float4 staging.
__global__ __launch_bounds__(256) void mask_conv3_k(
    const float* __restrict__ y, const float* __restrict__ wl,
    float* __restrict__ mpart) {
  __shared__ float ys[4][11][120];
  const int hx = blockIdx.x;  // 0..13
  const int b = blockIdx.y;   // 0..7
  const int z = blockIdx.z;   // 0..7
  const int ho0 = hx * 4;
  const int tid = threadIdx.x;
  const int r = tid / 56, c = tid - (tid / 56) * 56;  // valid tid<224

  // zero horizontal pads (cols 0,1,114..119) once
  for (int i = tid; i < 4 * 11 * 8; i += 256) {
    int ch = i / 88;
    int rem = i - ch * 88;
    int rr = rem / 8;
    int p = rem - rr * 8;
    int col = (p < 2) ? p : (112 + p);
    ys[ch][rr][col] = 0.f;
  }

  float acc[25];
#pragma unroll
  for (int k = 0; k < 25; ++k) acc[k] = 0.f;

  for (int c4 = 0; c4 < 2; ++c4) {
    const int cmbase = z * 8 + c4 * 4;
    __syncthreads();
    // stage 4 ch x 11 rows x 28 float4 (aligned)
    for (int i = tid; i < 4 * 11 * 28; i += 256) {
      int ch = i / 308;
      int rem = i - ch * 308;
      int rr = rem / 28;
      int j4 = rem - rr * 28;
      int hi = ho0 * 2 - 2 + rr;
      float4 v = {0.f, 0.f, 0.f, 0.f};
      if ((unsigned)hi < 112u)
        v = *(const float4*)&y[((size_t)(b * 64 + cmbase + ch) * 112 + hi) * 112 + j4 * 4];
      ys[ch][rr][2 + j4 * 4 + 0] = v.x;
      ys[ch][rr][2 + j4 * 4 + 1] = v.y;
      ys[ch][rr][2 + j4 * 4 + 2] = v.z;
      ys[ch][rr][2 + j4 * 4 + 3] = v.w;
    }
    __syncthreads();
    if (tid < 224) {
#pragma unroll
      for (int cml = 0; cml < 4; ++cml) {
        float p[25];
#pragma unroll
        for (int di = 0; di < 5; ++di)
#pragma unroll
          for (int dj = 0; dj < 5; ++dj)
            p[di * 5 + dj] = ys[cml][2 * r + di][2 * c + dj];
        const float* __restrict__ wb = wl + (size_t)(cmbase + cml) * 625;
#pragma unroll
        for (int tap = 0; tap < 25; ++tap) {
          float pv = p[tap];
#pragma unroll
          for (int k = 0; k < 25; ++k)
            acc[k] = fmaf(wb[tap * 25 + k], pv, acc[k]);
        }
      }
    }
  }
  if (tid < 224) {
    int sp = (ho0 + r) * 56 + c;
#pragma unroll
    for (int k = 0; k < 25; ++k)
      mpart[((size_t)(z * 8 + b) * 25 + k) * 3136 + sp] = acc[k];
  }
}

// ---------------------------------------------------------------- softmax (combine 8 partials + bias)
__global__ __launch_bounds__(256) void softmax2_k(
    const float* __restrict__ mpart, const float* __restrict__ be,
    float* __restrict__ msk) {
  int idx = blockIdx.x * 256 + threadIdx.x;
  if (idx >= 8 * 3136) return;
  int b = idx / 3136, sp = idx - (idx / 3136) * 3136;
  float v[25];
  float mx = -1e30f;
#pragma unroll
  for (int k = 0; k < 25; ++k) {
    size_t o = ((size_t)b * 25 + k) * 3136 + sp;
    float s = be[k];
#pragma unroll
    for (int z = 0; z < 8; ++z) s += mpart[(size_t)z * 627200 + o];
    v[k] = s;
    mx = fmaxf(mx, s);
  }
  float s = 0.f;
#pragma unroll
  for (int k = 0; k < 25; ++k) {
    v[k] = __expf(v[k] - mx);
    s += v[k];
  }
  float inv = 1.0f / s;
#pragma unroll
  for (int k = 0; k < 25; ++k)
    msk[((size_t)b * 25 + k) * 3136 + sp] = v[k] * inv;
}

// ---------------------------------------------------------------- carafe v2
__device__ __forceinline__ void stage_ch(float ysb[19][120],
                                         const float* __restrict__ hp,
                                         int ho0, int tid) {
  for (int i = tid; i < 532; i += 512) {
    int rr = i / 28;
    int c4 = (i - rr * 28) * 4;
    int hi = 2 * ho0 - 2 + rr;
    float4 v = {0.f, 0.f, 0.f, 0.f};
    if ((unsigned)hi < 112u) v = *(const float4*)&hp[hi * 112 + c4];
    ysb[rr][2 + c4 + 0] = v.x;
    ysb[rr][2 + c4 + 1] = v.y;
    ysb[rr][2 + c4 + 2] = v.z;
    ysb[rr][2 + c4 + 3] = v.w;
  }
}

__global__ __launch_bounds__(512) void carafe2_k(
    const float* __restrict__ h, const float* __restrict__ msk,
    const float* __restrict__ s2, const float* __restrict__ t2,
    float* __restrict__ h2) {
  __shared__ float ys[2][19][120];
  const int hx = blockIdx.x;   // 0..6
  const int b  = blockIdx.y;   // 0..7
  const int cz = blockIdx.z;   // 0..7
  const int ho0 = hx * 8;
  const int tid = threadIdx.x;
  const int r = tid / 56;
  const int c = tid - r * 56;

  for (int i = tid; i < 2 * 19 * 8; i += 512) {
    int bufi = i / 152;
    int rem = i - bufi * 152;
    int rr = rem / 8;
    int p = rem - rr * 8;
    int col = (p < 2) ? p : (112 + p);
    ys[bufi][rr][col] = 0.f;
  }

  float m[25];
  if (tid < 448) {
    const float* mp = msk + (size_t)b * 25 * 3136 + (ho0 + r) * 56 + c;
#pragma unroll
    for (int k = 0; k < 25; ++k) m[k] = mp[(size_t)k * 3136];
  }
  __syncthreads();

  const int c0 = cz * 48;
  stage_ch(ys[0], h + ((size_t)(b * 384 + c0) * 112) * 112, ho0, tid);
  __syncthreads();

  for (int ch = 0; ch < 48; ++ch) {
    const int bf = ch & 1;
    const int cc = c0 + ch;
    if (ch + 1 < 48)
      stage_ch(ys[bf ^ 1], h + ((size_t)(b * 384 + cc + 1) * 112) * 112, ho0, tid);
    if (tid < 448) {
      float acc = 0.f;
#pragma unroll
      for (int di = 0; di < 5; ++di) {
        const float* row = &ys[bf][2 * r + di][2 * c];
        float2 a01 = *(const float2*)&row[0];
        float2 a23 = *(const float2*)&row[2];
        float a4 = row[4];
        acc = fmaf(a01.x, m[di * 5 + 0], acc);
        acc = fmaf(a01.y, m[di * 5 + 1], acc);
        acc = fmaf(a23.x, m[di * 5 + 2], acc);
        acc = fmaf(a23.y, m[di * 5 + 3], acc);
        acc = fmaf(a4,    m[di * 5 + 4], acc);
      }
      float o = s2[cc] * acc + t2[cc];
      h2[((size_t)(b * 384 + cc) * 56 + ho0 + r) * 56 + c] =
          fminf(fmaxf(o, 0.f), 6.f);
    }
    __syncthreads();
  }
}

// ---------------------------------------------------------------- launch
extern "C" void kernel_launch(void* const* d_in, const int* in_sizes, int n_in,
                              void* d_out, int out_size, void* d_ws, size_t ws_size,
                              hipStream_t stream) {
  const float* x  = (const float*)d_in[0];
  const float* w1 = (const float*)d_in[1];
  const float* g1 = (const float*)d_in[2];
  const float* b1 = (const float*)d_in[3];
  const float* m1 = (const float*)d_in[4];
  const float* v1 = (const float*)d_in[5];
  const float* wc = (const float*)d_in[6];
  const float* bc = (const float*)d_in[7];
  const float* we = (const float*)d_in[8];
  const float* be = (const float*)d_in[9];
  const float* g2 = (const float*)d_in[10];
  const float* b2 = (const float*)d_in[11];
  const float* m2 = (const float*)d_in[12];
  const float* v2 = (const float*)d_in[13];
  const float* w2 = (const float*)d_in[14];
  const float* g3 = (const float*)d_in[15];
  const float* b3 = (const float*)d_in[16];
  const float* m3 = (const float*)d_in[17];
  const float* v3 = (const float*)d_in[18];
  float* out = (float*)d_out;

  float* ws = (float*)d_ws;
  float* h     = ws;                     // 38,535,168
  float* y     = h + 38535168;           //  6,422,528 (mask final aliases here)
  float* h2    = y + 6422528;            //  9,633,792 (mask partials alias here)
  float* w1f   = h2 + 9633792;           // 24576
  float* bias1 = w1f + 24576;            // 384
  float* w2f   = bias1 + 384;            // 49152
  float* bias3 = w2f + 49152;            // 128
  float* s2    = bias3 + 128;            // 384
  float* t2    = s2 + 384;               // 384
  float* wl    = t2 + 384;               // 40000
  float* mpart = h2;                     // 8*627,200 = 5,017,600 (alias, consumed before carafe)
  float* mskf  = y;                      // alias, y consumed before softmax writes

  fold_k<<<192, 256, 0, stream>>>(w1, g1, b1, m1, v1, g2, b2, m2, v2,
                                  w2, g3, b3, m3, v3,
                                  w1f, bias1, w2f, bias3, s2, t2);
  wtrans_k<<<157, 256, 0, stream>>>(we, wl);

  conv1x1_k<64, 1><<<dim3(196, 6, 8), 256, 0, stream>>>(x, w1f, bias1, h, 12544);
  conv1x1_k<384, 0><<<dim3(196, 1, 8), 256, 0, stream>>>(h, wc, bc, y, 12544);

  mask_conv3_k<<<dim3(14, 8, 8), 256, 0, stream>>>(y, wl, mpart);
  softmax2_k<<<98, 256, 0, stream>>>(mpart, be, mskf);

  carafe2_k<<<dim3(7, 8, 8), 512, 0, stream>>>(h, mskf, s2, t2, h2);

  conv1x1_k<384, 0><<<dim3(49, 2, 8), 256, 0, stream>>>(h2, w2f, bias3, out, 3136);
}

// Round 5
// 321.607 us; speedup vs baseline: 3.7355x; 1.3224x over previous
//
#include <hip/hip_runtime.h>
#include <hip/hip_bf16.h>

#define EPS 1e-5f

typedef _Float16 half8 __attribute__((ext_vector_type(8)));
typedef float f32x4 __attribute__((ext_vector_type(4)));

// ---------------------------------------------------------------- fold bn (+ f16 weight conversion)
__global__ __launch_bounds__(256) void fold_k(
    const float* __restrict__ w1, const float* __restrict__ g1, const float* __restrict__ b1,
    const float* __restrict__ m1, const float* __restrict__ v1,
    const float* __restrict__ wc,
    const float* __restrict__ g2, const float* __restrict__ b2,
    const float* __restrict__ m2, const float* __restrict__ v2,
    const float* __restrict__ w2, const float* __restrict__ g3, const float* __restrict__ b3,
    const float* __restrict__ m3, const float* __restrict__ v3,
    _Float16* __restrict__ w1h, float* __restrict__ bias1,
    _Float16* __restrict__ wch,
    _Float16* __restrict__ w2h, float* __restrict__ bias3,
    float* __restrict__ s2, float* __restrict__ t2) {
  int i = blockIdx.x * 256 + threadIdx.x;
  if (i < 384 * 64) {
    int o = i >> 6;
    float inv = g1[o] / sqrtf(v1[o] + EPS);
    w1h[i] = (_Float16)(w1[i] * inv);
  }
  if (i < 64 * 384) wch[i] = (_Float16)wc[i];
  if (i < 128 * 384) {
    int o = i / 384;
    float inv = g3[o] / sqrtf(v3[o] + EPS);
    w2h[i] = (_Float16)(w2[i] * inv);
  }
  if (i < 384) {
    float inv = g1[i] / sqrtf(v1[i] + EPS);
    bias1[i] = b1[i] - m1[i] * inv;
    float inv2 = g2[i] / sqrtf(v2[i] + EPS);
    s2[i] = inv2;
    t2[i] = b2[i] - m2[i] * inv2;
  }
  if (i < 128) {
    float inv = g3[i] / sqrtf(v3[i] + EPS);
    bias3[i] = b3[i] - m3[i] * inv;
  }
}

// ---------------------------------------------------------------- transpose mask weights
__global__ __launch_bounds__(256) void wtrans_k(const float* __restrict__ we,
                                               float* __restrict__ wl) {
  int i = blockIdx.x * 256 + threadIdx.x;
  if (i >= 40000) return;
  int k = i / 1600;
  int rem = i - k * 1600;
  int cm = rem / 25;
  int tap = rem - cm * 25;
  wl[(cm * 25 + tap) * 25 + k] = we[i];
}

// ---------------------------------------------------------------- 1x1 conv via f16 MFMA
// out[b][oc][px] = act( sum_ic W[oc][ic]*X[ic][px] + bias[oc] )
// Block: 256 thr = 4 waves; tile 64 oc x (NPF*64) px; K-step 32.
// mfma_f32_16x16x32_f16: A lane: W[oc=l&15][k=(l>>4)*8+j]; B lane:
// X[k=(l>>4)*8+j][px=l&15]; D: px=lane&15, oc=(lane>>4)*4+reg.
template <int IC, int NPF, int ACT>
__global__ __launch_bounds__(256) void gemm16_k(
    const float* __restrict__ in, const _Float16* __restrict__ wh,
    const float* __restrict__ bias, float* __restrict__ out, int npx) {
  constexpr int BPX = NPF * 64;   // px per block
  constexpr int QP = BPX / 4;     // float4 per ic row
  __shared__ _Float16 xh[BPX][40];  // transposed, row padded to 80 B
  const int tid = threadIdx.x;
  const int lane = tid & 63;
  const int w = tid >> 6;
  const int l15 = lane & 15;
  const int g = lane >> 4;
  const int wpx = w * NPF * 16;
  const int p0 = blockIdx.x * BPX;
  const int oc0 = blockIdx.y * 64;
  const int b = blockIdx.z;
  const int OCT = gridDim.y * 64;
  const float* inb = in + (size_t)b * IC * npx + p0;

  f32x4 acc[4][NPF];
#pragma unroll
  for (int fo = 0; fo < 4; ++fo)
#pragma unroll
    for (int pf = 0; pf < NPF; ++pf)
      acc[fo][pf] = (f32x4){0.f, 0.f, 0.f, 0.f};

  for (int kk = 0; kk < IC; kk += 32) {
    __syncthreads();
    // A fragments from global (L2-resident weights)
    half8 a[4];
#pragma unroll
    for (int fo = 0; fo < 4; ++fo)
      a[fo] = *(const half8*)&wh[(size_t)(oc0 + fo * 16 + l15) * IC + kk + g * 8];
    // stage X tile transposed into LDS (fp32 -> f16)
#pragma unroll
    for (int r = 0; r < QP / 8; ++r) {
      int s = tid + 256 * r;
      int ic = s / QP, q = s - (s / QP) * QP;
      float4 v = *(const float4*)&inb[(size_t)(kk + ic) * npx + q * 4];
      xh[q * 4 + 0][ic] = (_Float16)v.x;
      xh[q * 4 + 1][ic] = (_Float16)v.y;
      xh[q * 4 + 2][ic] = (_Float16)v.z;
      xh[q * 4 + 3][ic] = (_Float16)v.w;
    }
    __syncthreads();
    half8 xb[NPF];
#pragma unroll
    for (int pf = 0; pf < NPF; ++pf)
      xb[pf] = *(const half8*)&xh[wpx + pf * 16 + l15][g * 8];
#pragma unroll
    for (int fo = 0; fo < 4; ++fo)
#pragma unroll
      for (int pf = 0; pf < NPF; ++pf)
        acc[fo][pf] = __builtin_amdgcn_mfma_f32_16x16x32_f16(
            a[fo], xb[pf], acc[fo][pf], 0, 0, 0);
  }

#pragma unroll
  for (int fo = 0; fo < 4; ++fo) {
#pragma unroll
    for (int r = 0; r < 4; ++r) {
      int oc = oc0 + fo * 16 + g * 4 + r;
      float bz = bias[oc];
#pragma unroll
      for (int pf = 0; pf < NPF; ++pf) {
        float v = acc[fo][pf][r] + bz;
        if (ACT) v = fminf(fmaxf(v, 0.f), 6.f);
        out[((size_t)b * OCT + oc) * npx + p0 + wpx + pf * 16 + l15] = v;
      }
    }
  }
}

// ---------------------------------------------------------------- mask conv 5x5 s2 (v3)
__global__ __launch_bounds__(256) void mask_conv3_k(
    const float* __restrict__ y, const float* __restrict__ wl,
    float* __restrict__ mpart) {
  __shared__ float ys[4][11][120];
  const int hx = blockIdx.x;
  const int b = blockIdx.y;
  const int z = blockIdx.z;
  const int ho0 = hx * 4;
  const int tid = threadIdx.x;
  const int r = tid / 56, c = tid - (tid / 56) * 56;

  for (int i = tid; i < 4 * 11 * 8; i += 256) {
    int ch = i / 88;
    int rem = i - ch * 88;
    int rr = rem / 8;
    int p = rem - rr * 8;
    int col = (p < 2) ? p : (112 + p);
    ys[ch][rr][col] = 0.f;
  }

  float acc[25];
#pragma unroll
  for (int k = 0; k < 25; ++k) acc[k] = 0.f;

  for (int c4 = 0; c4 < 2; ++c4) {
    const int cmbase = z * 8 + c4 * 4;
    __syncthreads();
    for (int i = tid; i < 4 * 11 * 28; i += 256) {
      int ch = i / 308;
      int rem = i - ch * 308;
      int rr = rem / 28;
      int j4 = rem - rr * 28;
      int hi = ho0 * 2 - 2 + rr;
      float4 v = {0.f, 0.f, 0.f, 0.f};
      if ((unsigned)hi < 112u)
        v = *(const float4*)&y[((size_t)(b * 64 + cmbase + ch) * 112 + hi) * 112 + j4 * 4];
      ys[ch][rr][2 + j4 * 4 + 0] = v.x;
      ys[ch][rr][2 + j4 * 4 + 1] = v.y;
      ys[ch][rr][2 + j4 * 4 + 2] = v.z;
      ys[ch][rr][2 + j4 * 4 + 3] = v.w;
    }
    __syncthreads();
    if (tid < 224) {
#pragma unroll
      for (int cml = 0; cml < 4; ++cml) {
        float p[25];
#pragma unroll
        for (int di = 0; di < 5; ++di)
#pragma unroll
          for (int dj = 0; dj < 5; ++dj)
            p[di * 5 + dj] = ys[cml][2 * r + di][2 * c + dj];
        const float* __restrict__ wb = wl + (size_t)(cmbase + cml) * 625;
#pragma unroll
        for (int tap = 0; tap < 25; ++tap) {
          float pv = p[tap];
#pragma unroll
          for (int k = 0; k < 25; ++k)
            acc[k] = fmaf(wb[tap * 25 + k], pv, acc[k]);
        }
      }
    }
  }
  if (tid < 224) {
    int sp = (ho0 + r) * 56 + c;
#pragma unroll
    for (int k = 0; k < 25; ++k)
      mpart[((size_t)(z * 8 + b) * 25 + k) * 3136 + sp] = acc[k];
  }
}

// ---------------------------------------------------------------- softmax (combine 8 partials + bias)
__global__ __launch_bounds__(256) void softmax2_k(
    const float* __restrict__ mpart, const float* __restrict__ be,
    float* __restrict__ msk) {
  int idx = blockIdx.x * 256 + threadIdx.x;
  if (idx >= 8 * 3136) return;
  int b = idx / 3136, sp = idx - (idx / 3136) * 3136;
  float v[25];
  float mx = -1e30f;
#pragma unroll
  for (int k = 0; k < 25; ++k) {
    size_t o = ((size_t)b * 25 + k) * 3136 + sp;
    float s = be[k];
#pragma unroll
    for (int z = 0; z < 8; ++z) s += mpart[(size_t)z * 627200 + o];
    v[k] = s;
    mx = fmaxf(mx, s);
  }
  float s = 0.f;
#pragma unroll
  for (int k = 0; k < 25; ++k) {
    v[k] = __expf(v[k] - mx);
    s += v[k];
  }
  float inv = 1.0f / s;
#pragma unroll
  for (int k = 0; k < 25; ++k)
    msk[((size_t)b * 25 + k) * 3136 + sp] = v[k] * inv;
}

// ---------------------------------------------------------------- carafe v2
__device__ __forceinline__ void stage_ch(float ysb[19][120],
                                         const float* __restrict__ hp,
                                         int ho0, int tid) {
  for (int i = tid; i < 532; i += 512) {
    int rr = i / 28;
    int c4 = (i - rr * 28) * 4;
    int hi = 2 * ho0 - 2 + rr;
    float4 v = {0.f, 0.f, 0.f, 0.f};
    if ((unsigned)hi < 112u) v = *(const float4*)&hp[hi * 112 + c4];
    ysb[rr][2 + c4 + 0] = v.x;
    ysb[rr][2 + c4 + 1] = v.y;
    ysb[rr][2 + c4 + 2] = v.z;
    ysb[rr][2 + c4 + 3] = v.w;
  }
}

__global__ __launch_bounds__(512) void carafe2_k(
    const float* __restrict__ h, const float* __restrict__ msk,
    const float* __restrict__ s2, const float* __restrict__ t2,
    float* __restrict__ h2) {
  __shared__ float ys[2][19][120];
  const int hx = blockIdx.x;
  const int b  = blockIdx.y;
  const int cz = blockIdx.z;
  const int ho0 = hx * 8;
  const int tid = threadIdx.x;
  const int r = tid / 56;
  const int c = tid - r * 56;

  for (int i = tid; i < 2 * 19 * 8; i += 512) {
    int bufi = i / 152;
    int rem = i - bufi * 152;
    int rr = rem / 8;
    int p = rem - rr * 8;
    int col = (p < 2) ? p : (112 + p);
    ys[bufi][rr][col] = 0.f;
  }

  float m[25];
  if (tid < 448) {
    const float* mp = msk + (size_t)b * 25 * 3136 + (ho0 + r) * 56 + c;
#pragma unroll
    for (int k = 0; k < 25; ++k) m[k] = mp[(size_t)k * 3136];
  }
  __syncthreads();

  const int c0 = cz * 48;
  stage_ch(ys[0], h + ((size_t)(b * 384 + c0) * 112) * 112, ho0, tid);
  __syncthreads();

  for (int ch = 0; ch < 48; ++ch) {
    const int bf = ch & 1;
    const int cc = c0 + ch;
    if (ch + 1 < 48)
      stage_ch(ys[bf ^ 1], h + ((size_t)(b * 384 + cc + 1) * 112) * 112, ho0, tid);
    if (tid < 448) {
      float acc = 0.f;
#pragma unroll
      for (int di = 0; di < 5; ++di) {
        const float* row = &ys[bf][2 * r + di][2 * c];
        float2 a01 = *(const float2*)&row[0];
        float2 a23 = *(const float2*)&row[2];
        float a4 = row[4];
        acc = fmaf(a01.x, m[di * 5 + 0], acc);
        acc = fmaf(a01.y, m[di * 5 + 1], acc);
        acc = fmaf(a23.x, m[di * 5 + 2], acc);
        acc = fmaf(a23.y, m[di * 5 + 3], acc);
        acc = fmaf(a4,    m[di * 5 + 4], acc);
      }
      float o = s2[cc] * acc + t2[cc];
      h2[((size_t)(b * 384 + cc) * 56 + ho0 + r) * 56 + c] =
          fminf(fmaxf(o, 0.f), 6.f);
    }
    __syncthreads();
  }
}

// ---------------------------------------------------------------- launch
extern "C" void kernel_launch(void* const* d_in, const int* in_sizes, int n_in,
                              void* d_out, int out_size, void* d_ws, size_t ws_size,
                              hipStream_t stream) {
  const float* x  = (const float*)d_in[0];
  const float* w1 = (const float*)d_in[1];
  const float* g1 = (const float*)d_in[2];
  const float* b1 = (const float*)d_in[3];
  const float* m1 = (const float*)d_in[4];
  const float* v1 = (const float*)d_in[5];
  const float* wc = (const float*)d_in[6];
  const float* bc = (const float*)d_in[7];
  const float* we = (const float*)d_in[8];
  const float* be = (const float*)d_in[9];
  const float* g2 = (const float*)d_in[10];
  const float* b2 = (const float*)d_in[11];
  const float* m2 = (const float*)d_in[12];
  const float* v2 = (const float*)d_in[13];
  const float* w2 = (const float*)d_in[14];
  const float* g3 = (const float*)d_in[15];
  const float* b3 = (const float*)d_in[16];
  const float* m3 = (const float*)d_in[17];
  const float* v3 = (const float*)d_in[18];
  float* out = (float*)d_out;

  float* ws = (float*)d_ws;
  float* h     = ws;                     // 38,535,168
  float* y     = h + 38535168;           //  6,422,528 (mask final aliases here)
  float* h2    = y + 6422528;            //  9,633,792 (mask partials alias here)
  float* bias1 = h2 + 9633792;           // 384
  float* bias3 = bias1 + 384;            // 128
  float* s2    = bias3 + 128;            // 384
  float* t2    = s2 + 384;               // 384
  float* wl    = t2 + 384;               // 40000
  _Float16* w1h = (_Float16*)(wl + 40000);  // 24576 halves
  _Float16* wch = w1h + 24576;              // 24576 halves
  _Float16* w2h = wch + 24576;              // 49152 halves
  float* mpart = h2;                     // 8*627,200 alias, consumed before carafe
  float* mskf  = y;                      // alias, y consumed before softmax writes

  fold_k<<<192, 256, 0, stream>>>(w1, g1, b1, m1, v1, wc, g2, b2, m2, v2,
                                  w2, g3, b3, m3, v3,
                                  w1h, bias1, wch, w2h, bias3, s2, t2);
  wtrans_k<<<157, 256, 0, stream>>>(we, wl);

  // stage 1: h = relu6(bn1(conv1x1(x, w1)))
  gemm16_k<64, 2, 1><<<dim3(98, 6, 8), 256, 0, stream>>>(x, w1h, bias1, h, 12544);

  // compressor: y = conv1x1(h, wc) + bc
  gemm16_k<384, 2, 0><<<dim3(98, 1, 8), 256, 0, stream>>>(h, wch, bc, y, 12544);

  // mask conv (partials) + softmax (combine + bias)
  mask_conv3_k<<<dim3(14, 8, 8), 256, 0, stream>>>(y, wl, mpart);
  softmax2_k<<<98, 256, 0, stream>>>(mpart, be, mskf);

  // carafe + bn2 + relu6
  carafe2_k<<<dim3(7, 8, 8), 512, 0, stream>>>(h, mskf, s2, t2, h2);

  // final: out = bn3(conv1x1(h2, w2))
  gemm16_k<384, 1, 0><<<dim3(49, 2, 8), 256, 0, stream>>>(h2, w2h, bias3, out, 3136);
}

// Round 6
// 292.386 us; speedup vs baseline: 4.1088x; 1.0999x over previous
//
#include <hip/hip_runtime.h>
#include <hip/hip_bf16.h>

#define EPS 1e-5f

typedef _Float16 half8 __attribute__((ext_vector_type(8)));
typedef _Float16 half2v __attribute__((ext_vector_type(2)));
typedef float f32x4 __attribute__((ext_vector_type(4)));

// ---------------------------------------------------------------- fold bn (+ f16 weight conversion)
__global__ __launch_bounds__(256) void fold_k(
    const float* __restrict__ w1, const float* __restrict__ g1, const float* __restrict__ b1,
    const float* __restrict__ m1, const float* __restrict__ v1,
    const float* __restrict__ wc,
    const float* __restrict__ g2, const float* __restrict__ b2,
    const float* __restrict__ m2, const float* __restrict__ v2,
    const float* __restrict__ w2, const float* __restrict__ g3, const float* __restrict__ b3,
    const float* __restrict__ m3, const float* __restrict__ v3,
    _Float16* __restrict__ w1h, float* __restrict__ bias1,
    _Float16* __restrict__ wch,
    _Float16* __restrict__ w2h, float* __restrict__ bias3,
    float* __restrict__ s2, float* __restrict__ t2) {
  int i = blockIdx.x * 256 + threadIdx.x;
  if (i < 384 * 64) {
    int o = i >> 6;
    float inv = g1[o] / sqrtf(v1[o] + EPS);
    w1h[i] = (_Float16)(w1[i] * inv);
  }
  if (i < 64 * 384) wch[i] = (_Float16)wc[i];
  if (i < 128 * 384) {
    int o = i / 384;
    float inv = g3[o] / sqrtf(v3[o] + EPS);
    w2h[i] = (_Float16)(w2[i] * inv);
  }
  if (i < 384) {
    float inv = g1[i] / sqrtf(v1[i] + EPS);
    bias1[i] = b1[i] - m1[i] * inv;
    float inv2 = g2[i] / sqrtf(v2[i] + EPS);
    s2[i] = inv2;
    t2[i] = b2[i] - m2[i] * inv2;
  }
  if (i < 128) {
    float inv = g3[i] / sqrtf(v3[i] + EPS);
    bias3[i] = b3[i] - m3[i] * inv;
  }
}

// ---------------------------------------------------------------- transpose mask weights
__global__ __launch_bounds__(256) void wtrans_k(const float* __restrict__ we,
                                               float* __restrict__ wl) {
  int i = blockIdx.x * 256 + threadIdx.x;
  if (i >= 40000) return;
  int k = i / 1600;
  int rem = i - k * 1600;
  int cm = rem / 25;
  int tap = rem - cm * 25;
  wl[(cm * 25 + tap) * 25 + k] = we[i];
}

// ---------------------------------------------------------------- 1x1 conv via f16 MFMA
template <int IC, int NPF, int ACT>
__global__ __launch_bounds__(256) void gemm16_k(
    const float* __restrict__ in, const _Float16* __restrict__ wh,
    const float* __restrict__ bias, float* __restrict__ out, int npx) {
  constexpr int BPX = NPF * 64;
  constexpr int QP = BPX / 4;
  __shared__ _Float16 xh[BPX][40];
  const int tid = threadIdx.x;
  const int lane = tid & 63;
  const int w = tid >> 6;
  const int l15 = lane & 15;
  const int g = lane >> 4;
  const int wpx = w * NPF * 16;
  const int p0 = blockIdx.x * BPX;
  const int oc0 = blockIdx.y * 64;
  const int b = blockIdx.z;
  const int OCT = gridDim.y * 64;
  const float* inb = in + (size_t)b * IC * npx + p0;

  f32x4 acc[4][NPF];
#pragma unroll
  for (int fo = 0; fo < 4; ++fo)
#pragma unroll
    for (int pf = 0; pf < NPF; ++pf)
      acc[fo][pf] = (f32x4){0.f, 0.f, 0.f, 0.f};

  for (int kk = 0; kk < IC; kk += 32) {
    __syncthreads();
    half8 a[4];
#pragma unroll
    for (int fo = 0; fo < 4; ++fo)
      a[fo] = *(const half8*)&wh[(size_t)(oc0 + fo * 16 + l15) * IC + kk + g * 8];
#pragma unroll
    for (int r = 0; r < QP / 8; ++r) {
      int s = tid + 256 * r;
      int ic = s / QP, q = s - (s / QP) * QP;
      float4 v = *(const float4*)&inb[(size_t)(kk + ic) * npx + q * 4];
      xh[q * 4 + 0][ic] = (_Float16)v.x;
      xh[q * 4 + 1][ic] = (_Float16)v.y;
      xh[q * 4 + 2][ic] = (_Float16)v.z;
      xh[q * 4 + 3][ic] = (_Float16)v.w;
    }
    __syncthreads();
    half8 xb[NPF];
#pragma unroll
    for (int pf = 0; pf < NPF; ++pf)
      xb[pf] = *(const half8*)&xh[wpx + pf * 16 + l15][g * 8];
#pragma unroll
    for (int fo = 0; fo < 4; ++fo)
#pragma unroll
      for (int pf = 0; pf < NPF; ++pf)
        acc[fo][pf] = __builtin_amdgcn_mfma_f32_16x16x32_f16(
            a[fo], xb[pf], acc[fo][pf], 0, 0, 0);
  }

#pragma unroll
  for (int fo = 0; fo < 4; ++fo) {
#pragma unroll
    for (int r = 0; r < 4; ++r) {
      int oc = oc0 + fo * 16 + g * 4 + r;
      float bz = bias[oc];
#pragma unroll
      for (int pf = 0; pf < NPF; ++pf) {
        float v = acc[fo][pf][r] + bz;
        if (ACT) v = fminf(fmaxf(v, 0.f), 6.f);
        out[((size_t)b * OCT + oc) * npx + p0 + wpx + pf * 16 + l15] = v;
      }
    }
  }
}

// ---------------------------------------------------------------- mask conv 5x5 s2 (v4)
// 4 out rows x 56 cols; 8 channels staged as f16 in ONE phase; single
// straight-line 5000-FMA compute. grid (14, 8, 8).
__global__ __launch_bounds__(256) void mask_conv4_k(
    const float* __restrict__ y, const float* __restrict__ wl,
    float* __restrict__ mpart) {
  __shared__ _Float16 ysh[8][11][120];
  const int hx = blockIdx.x;
  const int b = blockIdx.y;
  const int z = blockIdx.z;
  const int ho0 = hx * 4;
  const int tid = threadIdx.x;
  const int r = tid / 56, c = tid - (tid / 56) * 56;
  const int cmbase = z * 8;

  // zero horizontal pads (cols 0,1,114..119)
  for (int i = tid; i < 8 * 11 * 8; i += 256) {
    int ch = i / 88;
    int rem = i - ch * 88;
    int rr = rem / 8;
    int p = rem - rr * 8;
    int col = (p < 2) ? p : (112 + p);
    ysh[ch][rr][col] = (_Float16)0.f;
  }

  // stage 8 ch x 11 rows x 28 float4 -> f16
  for (int i = tid; i < 8 * 11 * 28; i += 256) {
    int ch = i / 308;
    int rem = i - ch * 308;
    int rr = rem / 28;
    int j4 = rem - rr * 28;
    int hi = ho0 * 2 - 2 + rr;
    float4 v = {0.f, 0.f, 0.f, 0.f};
    if ((unsigned)hi < 112u)
      v = *(const float4*)&y[((size_t)(b * 64 + cmbase + ch) * 112 + hi) * 112 + j4 * 4];
    half2v lo = {(_Float16)v.x, (_Float16)v.y};
    half2v hi2 = {(_Float16)v.z, (_Float16)v.w};
    *(half2v*)&ysh[ch][rr][2 + j4 * 4] = lo;
    *(half2v*)&ysh[ch][rr][4 + j4 * 4] = hi2;
  }
  __syncthreads();

  if (tid < 224) {
    float acc[25];
#pragma unroll
    for (int k = 0; k < 25; ++k) acc[k] = 0.f;
#pragma unroll
    for (int cml = 0; cml < 8; ++cml) {
      float p[25];
#pragma unroll
      for (int di = 0; di < 5; ++di)
#pragma unroll
        for (int dj = 0; dj < 5; ++dj)
          p[di * 5 + dj] = (float)ysh[cml][2 * r + di][2 * c + dj];
      const float* __restrict__ wb = wl + (size_t)(cmbase + cml) * 625;
#pragma unroll
      for (int tap = 0; tap < 25; ++tap) {
        float pv = p[tap];
#pragma unroll
        for (int k = 0; k < 25; ++k)
          acc[k] = fmaf(wb[tap * 25 + k], pv, acc[k]);
      }
    }
    int sp = (ho0 + r) * 56 + c;
#pragma unroll
    for (int k = 0; k < 25; ++k)
      mpart[((size_t)(z * 8 + b) * 25 + k) * 3136 + sp] = acc[k];
  }
}

// ---------------------------------------------------------------- softmax (combine 8 partials + bias)
__global__ __launch_bounds__(256) void softmax2_k(
    const float* __restrict__ mpart, const float* __restrict__ be,
    float* __restrict__ msk) {
  int idx = blockIdx.x * 256 + threadIdx.x;
  if (idx >= 8 * 3136) return;
  int b = idx / 3136, sp = idx - (idx / 3136) * 3136;
  float v[25];
  float mx = -1e30f;
#pragma unroll
  for (int k = 0; k < 25; ++k) {
    size_t o = ((size_t)b * 25 + k) * 3136 + sp;
    float s = be[k];
#pragma unroll
    for (int z = 0; z < 8; ++z) s += mpart[(size_t)z * 627200 + o];
    v[k] = s;
    mx = fmaxf(mx, s);
  }
  float s = 0.f;
#pragma unroll
  for (int k = 0; k < 25; ++k) {
    v[k] = __expf(v[k] - mx);
    s += v[k];
  }
  float inv = 1.0f / s;
#pragma unroll
  for (int k = 0; k < 25; ++k)
    msk[((size_t)b * 25 + k) * 3136 + sp] = v[k] * inv;
}

// ---------------------------------------------------------------- carafe v3
// grid (7, 8, 16): 24 channels/block, 2 channels staged per phase,
// double-buffered. 512 threads; 12 barim phases instead of 48.
__device__ __forceinline__ void stage_pair(float dst[2][19][120],
                                           const float* __restrict__ hbase,
                                           int ho0, int tid) {
  for (int i = tid; i < 1064; i += 512) {
    int ch = i / 532;
    int rem = i - ch * 532;
    int rr = rem / 28;
    int c4 = (rem - rr * 28) * 4;
    int hi = 2 * ho0 - 2 + rr;
    float4 v = {0.f, 0.f, 0.f, 0.f};
    if ((unsigned)hi < 112u)
      v = *(const float4*)&hbase[(size_t)ch * 12544 + hi * 112 + c4];
    dst[ch][rr][2 + c4 + 0] = v.x;
    dst[ch][rr][2 + c4 + 1] = v.y;
    dst[ch][rr][2 + c4 + 2] = v.z;
    dst[ch][rr][2 + c4 + 3] = v.w;
  }
}

__global__ __launch_bounds__(512) void carafe3_k(
    const float* __restrict__ h, const float* __restrict__ msk,
    const float* __restrict__ s2, const float* __restrict__ t2,
    float* __restrict__ h2) {
  __shared__ float ys[2][2][19][120];
  const int hx = blockIdx.x;   // 0..6
  const int b  = blockIdx.y;   // 0..7
  const int cz = blockIdx.z;   // 0..15
  const int ho0 = hx * 8;
  const int tid = threadIdx.x;
  const int r = tid / 56;
  const int c = tid - r * 56;
  const int c0 = cz * 24;

  // zero horizontal pads (cols 0,1,114..119; both bufs, both ch)
  for (int i = tid; i < 2 * 2 * 19 * 8; i += 512) {
    int bufi = i / 304;
    int rem = i - bufi * 304;
    int ch = rem / 152;
    int rem2 = rem - ch * 152;
    int rr = rem2 / 8;
    int p = rem2 - rr * 8;
    int col = (p < 2) ? p : (112 + p);
    ys[bufi][ch][rr][col] = 0.f;
  }

  // mask -> registers (reused for all 24 channels)
  float m[25];
  if (tid < 448) {
    const float* mp = msk + (size_t)b * 25 * 3136 + (ho0 + r) * 56 + c;
#pragma unroll
    for (int k = 0; k < 25; ++k) m[k] = mp[(size_t)k * 3136];
  }
  __syncthreads();

  stage_pair(ys[0], h + (size_t)(b * 384 + c0) * 12544, ho0, tid);
  __syncthreads();

#pragma unroll
  for (int p = 0; p < 12; ++p) {
    const int bf = p & 1;
    if (p + 1 < 12)
      stage_pair(ys[bf ^ 1], h + (size_t)(b * 384 + c0 + 2 * (p + 1)) * 12544,
                 ho0, tid);
    if (tid < 448) {
#pragma unroll
      for (int cl = 0; cl < 2; ++cl) {
        const int cc = c0 + 2 * p + cl;
        float acc = 0.f;
#pragma unroll
        for (int di = 0; di < 5; ++di) {
          const float* row = &ys[bf][cl][2 * r + di][2 * c];
          float2 a01 = *(const float2*)&row[0];
          float2 a23 = *(const float2*)&row[2];
          float a4 = row[4];
          acc = fmaf(a01.x, m[di * 5 + 0], acc);
          acc = fmaf(a01.y, m[di * 5 + 1], acc);
          acc = fmaf(a23.x, m[di * 5 + 2], acc);
          acc = fmaf(a23.y, m[di * 5 + 3], acc);
          acc = fmaf(a4,    m[di * 5 + 4], acc);
        }
        float o = s2[cc] * acc + t2[cc];
        h2[((size_t)(b * 384 + cc) * 56 + ho0 + r) * 56 + c] =
            fminf(fmaxf(o, 0.f), 6.f);
      }
    }
    __syncthreads();
  }
}

// ---------------------------------------------------------------- launch
extern "C" void kernel_launch(void* const* d_in, const int* in_sizes, int n_in,
                              void* d_out, int out_size, void* d_ws, size_t ws_size,
                              hipStream_t stream) {
  const float* x  = (const float*)d_in[0];
  const float* w1 = (const float*)d_in[1];
  const float* g1 = (const float*)d_in[2];
  const float* b1 = (const float*)d_in[3];
  const float* m1 = (const float*)d_in[4];
  const float* v1 = (const float*)d_in[5];
  const float* wc = (const float*)d_in[6];
  const float* bc = (const float*)d_in[7];
  const float* we = (const float*)d_in[8];
  const float* be = (const float*)d_in[9];
  const float* g2 = (const float*)d_in[10];
  const float* b2 = (const float*)d_in[11];
  const float* m2 = (const float*)d_in[12];
  const float* v2 = (const float*)d_in[13];
  const float* w2 = (const float*)d_in[14];
  const float* g3 = (const float*)d_in[15];
  const float* b3 = (const float*)d_in[16];
  const float* m3 = (const float*)d_in[17];
  const float* v3 = (const float*)d_in[18];
  float* out = (float*)d_out;

  float* ws = (float*)d_ws;
  float* h     = ws;                     // 38,535,168
  float* y     = h + 38535168;           //  6,422,528 (mask final aliases here)
  float* h2    = y + 6422528;            //  9,633,792 (mask partials alias here)
  float* bias1 = h2 + 9633792;           // 384
  float* bias3 = bias1 + 384;            // 128
  float* s2    = bias3 + 128;            // 384
  float* t2    = s2 + 384;               // 384
  float* wl    = t2 + 384;               // 40000
  _Float16* w1h = (_Float16*)(wl + 40000);  // 24576 halves
  _Float16* wch = w1h + 24576;              // 24576 halves
  _Float16* w2h = wch + 24576;              // 49152 halves
  float* mpart = h2;                     // 8*627,200 alias, consumed before carafe
  float* mskf  = y;                      // alias, y consumed before softmax writes

  fold_k<<<192, 256, 0, stream>>>(w1, g1, b1, m1, v1, wc, g2, b2, m2, v2,
                                  w2, g3, b3, m3, v3,
                                  w1h, bias1, wch, w2h, bias3, s2, t2);
  wtrans_k<<<157, 256, 0, stream>>>(we, wl);

  gemm16_k<64, 2, 1><<<dim3(98, 6, 8), 256, 0, stream>>>(x, w1h, bias1, h, 12544);
  gemm16_k<384, 2, 0><<<dim3(98, 1, 8), 256, 0, stream>>>(h, wch, bc, y, 12544);

  mask_conv4_k<<<dim3(14, 8, 8), 256, 0, stream>>>(y, wl, mpart);
  softmax2_k<<<98, 256, 0, stream>>>(mpart, be, mskf);

  carafe3_k<<<dim3(7, 8, 16), 512, 0, stream>>>(h, mskf, s2, t2, h2);

  gemm16_k<384, 1, 0><<<dim3(49, 2, 8), 256, 0, stream>>>(h2, w2h, bias3, out, 3136);
}

// Round 7
// 253.768 us; speedup vs baseline: 4.7341x; 1.1522x over previous
//
#include <hip/hip_runtime.h>
#include <hip/hip_bf16.h>

#define EPS 1e-5f

typedef _Float16 half8 __attribute__((ext_vector_type(8)));
typedef _Float16 half4 __attribute__((ext_vector_type(4)));
typedef float f32x4 __attribute__((ext_vector_type(4)));

// ---------------------------------------------------------------- fold bn (+ f16 weight conversion)
__global__ __launch_bounds__(256) void fold_k(
    const float* __restrict__ w1, const float* __restrict__ g1, const float* __restrict__ b1,
    const float* __restrict__ m1, const float* __restrict__ v1,
    const float* __restrict__ wc,
    const float* __restrict__ g2, const float* __restrict__ b2,
    const float* __restrict__ m2, const float* __restrict__ v2,
    const float* __restrict__ w2, const float* __restrict__ g3, const float* __restrict__ b3,
    const float* __restrict__ m3, const float* __restrict__ v3,
    _Float16* __restrict__ w1h, float* __restrict__ bias1,
    _Float16* __restrict__ wch,
    _Float16* __restrict__ w2h, float* __restrict__ bias3,
    float* __restrict__ s2, float* __restrict__ t2) {
  int i = blockIdx.x * 256 + threadIdx.x;
  if (i < 384 * 64) {
    int o = i >> 6;
    float inv = g1[o] / sqrtf(v1[o] + EPS);
    w1h[i] = (_Float16)(w1[i] * inv);
  }
  if (i < 64 * 384) wch[i] = (_Float16)wc[i];
  if (i < 128 * 384) {
    int o = i / 384;
    float inv = g3[o] / sqrtf(v3[o] + EPS);
    w2h[i] = (_Float16)(w2[i] * inv);
  }
  if (i < 384) {
    float inv = g1[i] / sqrtf(v1[i] + EPS);
    bias1[i] = b1[i] - m1[i] * inv;
    float inv2 = g2[i] / sqrtf(v2[i] + EPS);
    s2[i] = inv2;
    t2[i] = b2[i] - m2[i] * inv2;
  }
  if (i < 128) {
    float inv = g3[i] / sqrtf(v3[i] + EPS);
    bias3[i] = b3[i] - m3[i] * inv;
  }
}

// ---------------------------------------------------------------- transpose mask weights
__global__ __launch_bounds__(256) void wtrans_k(const float* __restrict__ we,
                                               float* __restrict__ wl) {
  int i = blockIdx.x * 256 + threadIdx.x;
  if (i >= 40000) return;
  int k = i / 1600;
  int rem = i - k * 1600;
  int cm = rem / 25;
  int tap = rem - cm * 25;
  wl[(cm * 25 + tap) * 25 + k] = we[i];
}

// ---------------------------------------------------------------- 1x1 conv via f16 MFMA (v2)
// Conflict-free staging: thread gathers 4 elems along k (4 coalesced loads),
// writes one contiguous half4 -> LDS. xh[px][40] rows (80 B).
template <int IC, int NPF, int ACT, typename TI, typename TO>
__global__ __launch_bounds__(256) void gemm16_k(
    const TI* __restrict__ in, const _Float16* __restrict__ wh,
    const float* __restrict__ bias, TO* __restrict__ out, int npx) {
  constexpr int BPX = NPF * 64;
  constexpr int L2B = (BPX == 128) ? 7 : 6;
  __shared__ _Float16 xh[BPX][40];
  const int tid = threadIdx.x;
  const int lane = tid & 63;
  const int w = tid >> 6;
  const int l15 = lane & 15;
  const int g = lane >> 4;
  const int wpx = w * NPF * 16;
  const int p0 = blockIdx.x * BPX;
  const int oc0 = blockIdx.y * 64;
  const int b = blockIdx.z;
  const int OCT = gridDim.y * 64;
  const TI* inb = in + (size_t)b * IC * npx + p0;

  f32x4 acc[4][NPF];
#pragma unroll
  for (int fo = 0; fo < 4; ++fo)
#pragma unroll
    for (int pf = 0; pf < NPF; ++pf)
      acc[fo][pf] = (f32x4){0.f, 0.f, 0.f, 0.f};

  for (int kk = 0; kk < IC; kk += 32) {
    __syncthreads();
    half8 a[4];
#pragma unroll
    for (int fo = 0; fo < 4; ++fo)
      a[fo] = *(const half8*)&wh[(size_t)(oc0 + fo * 16 + l15) * IC + kk + g * 8];
    // stage: gather 4 along k, one half4 write (conflict-free)
#pragma unroll
    for (int i = 0; i < NPF * 2; ++i) {
      int slot = tid + 256 * i;
      int px = slot & (BPX - 1);
      int kq = slot >> L2B;  // 0..7
      const TI* src = inb + (size_t)(kk + kq * 4) * npx + px;
      half4 v = {(_Float16)src[0], (_Float16)src[npx],
                 (_Float16)src[2 * npx], (_Float16)src[3 * npx]};
      *(half4*)&xh[px][kq * 4] = v;
    }
    __syncthreads();
    half8 xb[NPF];
#pragma unroll
    for (int pf = 0; pf < NPF; ++pf)
      xb[pf] = *(const half8*)&xh[wpx + pf * 16 + l15][g * 8];
#pragma unroll
    for (int fo = 0; fo < 4; ++fo)
#pragma unroll
      for (int pf = 0; pf < NPF; ++pf)
        acc[fo][pf] = __builtin_amdgcn_mfma_f32_16x16x32_f16(
            a[fo], xb[pf], acc[fo][pf], 0, 0, 0);
  }

#pragma unroll
  for (int fo = 0; fo < 4; ++fo) {
#pragma unroll
    for (int r = 0; r < 4; ++r) {
      int oc = oc0 + fo * 16 + g * 4 + r;
      float bz = bias[oc];
#pragma unroll
      for (int pf = 0; pf < NPF; ++pf) {
        float v = acc[fo][pf][r] + bz;
        if (ACT) v = fminf(fmaxf(v, 0.f), 6.f);
        out[((size_t)b * OCT + oc) * npx + p0 + wpx + pf * 16 + l15] = (TO)v;
      }
    }
  }
}

// ---------------------------------------------------------------- mask conv 5x5 s2 (v5, f16 input)
// 4 out rows x 56 cols; 8 f16 channels staged (pure 16B copy) in one phase.
// ysh rows 128-wide, data at col 8 (16B-aligned half8 writes).
__global__ __launch_bounds__(256) void mask_conv4_k(
    const _Float16* __restrict__ y, const float* __restrict__ wl,
    float* __restrict__ mpart) {
  __shared__ _Float16 ysh[8][11][128];
  const int hx = blockIdx.x;
  const int b = blockIdx.y;
  const int z = blockIdx.z;
  const int ho0 = hx * 4;
  const int tid = threadIdx.x;
  const int r = tid / 56, c = tid - (tid / 56) * 56;
  const int cmbase = z * 8;

  // zero all (pads + OOB rows)
  for (int i = tid; i < 8 * 11 * 128 / 2; i += 256)
    ((uint*)ysh)[i] = 0u;
  __syncthreads();

  // stage 8 ch x 11 rows x 14 half8 (no conversion)
  for (int i = 0; i < 5; ++i) {
    int slot = tid + 256 * i;
    if (slot < 1232) {
      int ch = slot / 154;
      int rem = slot - ch * 154;
      int rr = rem / 14;
      int j8 = rem - rr * 14;
      int hi = ho0 * 2 - 2 + rr;
      if ((unsigned)hi < 112u) {
        half8 v = *(const half8*)&y[((size_t)(b * 64 + cmbase + ch) * 112 + hi) * 112 + j8 * 8];
        *(half8*)&ysh[ch][rr][8 + j8 * 8] = v;
      }
    }
  }
  __syncthreads();

  if (tid < 224) {
    float acc[25];
#pragma unroll
    for (int k = 0; k < 25; ++k) acc[k] = 0.f;
#pragma unroll
    for (int cml = 0; cml < 8; ++cml) {
      float p[25];
#pragma unroll
      for (int di = 0; di < 5; ++di)
#pragma unroll
        for (int dj = 0; dj < 5; ++dj)
          p[di * 5 + dj] = (float)ysh[cml][2 * r + di][2 * c + dj + 6];
      const float* __restrict__ wb = wl + (size_t)(cmbase + cml) * 625;
#pragma unroll
      for (int tap = 0; tap < 25; ++tap) {
        float pv = p[tap];
#pragma unroll
        for (int k = 0; k < 25; ++k)
          acc[k] = fmaf(wb[tap * 25 + k], pv, acc[k]);
      }
    }
    int sp = (ho0 + r) * 56 + c;
#pragma unroll
    for (int k = 0; k < 25; ++k)
      mpart[((size_t)(z * 8 + b) * 25 + k) * 3136 + sp] = acc[k];
  }
}

// ---------------------------------------------------------------- softmax (combine 8 partials + bias)
__global__ __launch_bounds__(256) void softmax2_k(
    const float* __restrict__ mpart, const float* __restrict__ be,
    float* __restrict__ msk) {
  int idx = blockIdx.x * 256 + threadIdx.x;
  if (idx >= 8 * 3136) return;
  int b = idx / 3136, sp = idx - (idx / 3136) * 3136;
  float v[25];
  float mx = -1e30f;
#pragma unroll
  for (int k = 0; k < 25; ++k) {
    size_t o = ((size_t)b * 25 + k) * 3136 + sp;
    float s = be[k];
#pragma unroll
    for (int z = 0; z < 8; ++z) s += mpart[(size_t)z * 627200 + o];
    v[k] = s;
    mx = fmaxf(mx, s);
  }
  float s = 0.f;
#pragma unroll
  for (int k = 0; k < 25; ++k) {
    v[k] = __expf(v[k] - mx);
    s += v[k];
  }
  float inv = 1.0f / s;
#pragma unroll
  for (int k = 0; k < 25; ++k)
    msk[((size_t)b * 25 + k) * 3136 + sp] = v[k] * inv;
}

// ---------------------------------------------------------------- carafe v4 (f16 h input, f16 h2 out)
// LDS f32 rows 120-wide, data at col 4 (aligned float4 writes).
__device__ __forceinline__ void stage_pair(float dst[2][19][120],
                                           const _Float16* __restrict__ hbase,
                                           int ho0, int tid) {
  for (int i = tid; i < 2 * 19 * 14; i += 512) {
    int ch = i / 266;
    int rem = i - ch * 266;
    int rr = rem / 14;
    int j8 = rem - rr * 14;
    int hi = 2 * ho0 - 2 + rr;
    float4 lo = {0.f, 0.f, 0.f, 0.f}, hi4 = {0.f, 0.f, 0.f, 0.f};
    if ((unsigned)hi < 112u) {
      half8 v = *(const half8*)&hbase[(size_t)ch * 12544 + hi * 112 + j8 * 8];
      lo = (float4){(float)v[0], (float)v[1], (float)v[2], (float)v[3]};
      hi4 = (float4){(float)v[4], (float)v[5], (float)v[6], (float)v[7]};
    }
    *(float4*)&dst[ch][rr][4 + j8 * 8] = lo;
    *(float4*)&dst[ch][rr][8 + j8 * 8] = hi4;
  }
}

__global__ __launch_bounds__(512) void carafe3_k(
    const _Float16* __restrict__ h, const float* __restrict__ msk,
    const float* __restrict__ s2, const float* __restrict__ t2,
    _Float16* __restrict__ h2) {
  __shared__ float ys[2][2][19][120];
  const int hx = blockIdx.x;   // 0..6
  const int b  = blockIdx.y;   // 0..7
  const int cz = blockIdx.z;   // 0..15
  const int ho0 = hx * 8;
  const int tid = threadIdx.x;
  const int r = tid / 56;
  const int c = tid - r * 56;
  const int c0 = cz * 24;

  // zero pads: cols {0..3, 116..119} per row, both bufs/ch
  for (int i = tid; i < 2 * 2 * 19 * 8; i += 512) {
    int bufi = i / 304;
    int rem = i - bufi * 304;
    int ch = rem / 152;
    int rem2 = rem - ch * 152;
    int rr = rem2 / 8;
    int p = rem2 - rr * 8;
    int col = (p < 4) ? p : (112 + p);
    ys[bufi][ch][rr][col] = 0.f;
  }

  float m[25];
  if (tid < 448) {
    const float* mp = msk + (size_t)b * 25 * 3136 + (ho0 + r) * 56 + c;
#pragma unroll
    for (int k = 0; k < 25; ++k) m[k] = mp[(size_t)k * 3136];
  }
  __syncthreads();

  stage_pair(ys[0], h + (size_t)(b * 384 + c0) * 12544, ho0, tid);
  __syncthreads();

#pragma unroll
  for (int p = 0; p < 12; ++p) {
    const int bf = p & 1;
    if (p + 1 < 12)
      stage_pair(ys[bf ^ 1], h + (size_t)(b * 384 + c0 + 2 * (p + 1)) * 12544,
                 ho0, tid);
    if (tid < 448) {
#pragma unroll
      for (int cl = 0; cl < 2; ++cl) {
        const int cc = c0 + 2 * p + cl;
        float acc = 0.f;
#pragma unroll
        for (int di = 0; di < 5; ++di) {
          const float* row = &ys[bf][cl][2 * r + di][2 * c + 2];
          float2 a01 = *(const float2*)&row[0];
          float2 a23 = *(const float2*)&row[2];
          float a4 = row[4];
          acc = fmaf(a01.x, m[di * 5 + 0], acc);
          acc = fmaf(a01.y, m[di * 5 + 1], acc);
          acc = fmaf(a23.x, m[di * 5 + 2], acc);
          acc = fmaf(a23.y, m[di * 5 + 3], acc);
          acc = fmaf(a4,    m[di * 5 + 4], acc);
        }
        float o = s2[cc] * acc + t2[cc];
        h2[((size_t)(b * 384 + cc) * 56 + ho0 + r) * 56 + c] =
            (_Float16)fminf(fmaxf(o, 0.f), 6.f);
      }
    }
    __syncthreads();
  }
}

// ---------------------------------------------------------------- launch
extern "C" void kernel_launch(void* const* d_in, const int* in_sizes, int n_in,
                              void* d_out, int out_size, void* d_ws, size_t ws_size,
                              hipStream_t stream) {
  const float* x  = (const float*)d_in[0];
  const float* w1 = (const float*)d_in[1];
  const float* g1 = (const float*)d_in[2];
  const float* b1 = (const float*)d_in[3];
  const float* m1 = (const float*)d_in[4];
  const float* v1 = (const float*)d_in[5];
  const float* wc = (const float*)d_in[6];
  const float* bc = (const float*)d_in[7];
  const float* we = (const float*)d_in[8];
  const float* be = (const float*)d_in[9];
  const float* g2 = (const float*)d_in[10];
  const float* b2 = (const float*)d_in[11];
  const float* m2 = (const float*)d_in[12];
  const float* v2 = (const float*)d_in[13];
  const float* w2 = (const float*)d_in[14];
  const float* g3 = (const float*)d_in[15];
  const float* b3 = (const float*)d_in[16];
  const float* m3 = (const float*)d_in[17];
  const float* v3 = (const float*)d_in[18];
  float* out = (float*)d_out;

  // workspace layout (no aliasing needed: ~135 MB total)
  _Float16* hq  = (_Float16*)d_ws;          // 38,535,168 halves
  _Float16* yq  = hq + 38535168;            //  6,422,528 halves
  _Float16* h2q = yq + 6422528;             //  9,633,792 halves
  float* mpart  = (float*)(h2q + 9633792);  //  5,017,600 floats
  float* mskf   = mpart + 5017600;          //    627,200 floats
  float* bias1  = mskf + 627200;            // 384
  float* bias3  = bias1 + 384;              // 128
  float* s2     = bias3 + 128;              // 384
  float* t2     = s2 + 384;                 // 384
  float* wl     = t2 + 384;                 // 40000
  _Float16* w1h = (_Float16*)(wl + 40000);  // 24576 halves
  _Float16* wch = w1h + 24576;              // 24576 halves
  _Float16* w2h = wch + 24576;              // 49152 halves

  fold_k<<<192, 256, 0, stream>>>(w1, g1, b1, m1, v1, wc, g2, b2, m2, v2,
                                  w2, g3, b3, m3, v3,
                                  w1h, bias1, wch, w2h, bias3, s2, t2);
  wtrans_k<<<157, 256, 0, stream>>>(we, wl);

  // stage 1: h = relu6(bn1(conv1x1(x, w1)))  [fp32 in, f16 out]
  gemm16_k<64, 2, 1, float, _Float16>
      <<<dim3(98, 6, 8), 256, 0, stream>>>(x, w1h, bias1, hq, 12544);

  // compressor: y = conv1x1(h, wc) + bc  [f16 in, f16 out]
  gemm16_k<384, 2, 0, _Float16, _Float16>
      <<<dim3(98, 1, 8), 256, 0, stream>>>(hq, wch, bc, yq, 12544);

  // mask conv (partials) + softmax
  mask_conv4_k<<<dim3(14, 8, 8), 256, 0, stream>>>(yq, wl, mpart);
  softmax2_k<<<98, 256, 0, stream>>>(mpart, be, mskf);

  // carafe + bn2 + relu6  [f16 in/out]
  carafe3_k<<<dim3(7, 8, 16), 512, 0, stream>>>(hq, mskf, s2, t2, h2q);

  // final: out = bn3(conv1x1(h2, w2))  [f16 in, fp32 out]
  gemm16_k<384, 1, 0, _Float16, float>
      <<<dim3(49, 2, 8), 256, 0, stream>>>(h2q, w2h, bias3, out, 3136);
}

// Round 8
// 163.188 us; speedup vs baseline: 7.3618x; 1.5551x over previous
//
#include <hip/hip_runtime.h>
#include <hip/hip_bf16.h>

#define EPS 1e-5f

typedef _Float16 half8 __attribute__((ext_vector_type(8)));
typedef _Float16 half4 __attribute__((ext_vector_type(4)));
typedef _Float16 half2v __attribute__((ext_vector_type(2)));
typedef float f32x4 __attribute__((ext_vector_type(4)));

// ---------------------------------------------------------------- fold bn (+ f16 weight conversion)
__global__ __launch_bounds__(256) void fold_k(
    const float* __restrict__ w1, const float* __restrict__ g1, const float* __restrict__ b1,
    const float* __restrict__ m1, const float* __restrict__ v1,
    const float* __restrict__ wc,
    const float* __restrict__ g2, const float* __restrict__ b2,
    const float* __restrict__ m2, const float* __restrict__ v2,
    const float* __restrict__ w2, const float* __restrict__ g3, const float* __restrict__ b3,
    const float* __restrict__ m3, const float* __restrict__ v3,
    _Float16* __restrict__ w1h, float* __restrict__ bias1,
    _Float16* __restrict__ wch,
    _Float16* __restrict__ w2h, float* __restrict__ bias3,
    float* __restrict__ s2, float* __restrict__ t2) {
  int i = blockIdx.x * 256 + threadIdx.x;
  if (i < 384 * 64) {
    int o = i >> 6;
    float inv = g1[o] / sqrtf(v1[o] + EPS);
    w1h[i] = (_Float16)(w1[i] * inv);
  }
  if (i < 64 * 384) wch[i] = (_Float16)wc[i];
  if (i < 128 * 384) {
    int o = i / 384;
    float inv = g3[o] / sqrtf(v3[o] + EPS);
    w2h[i] = (_Float16)(w2[i] * inv);
  }
  if (i < 384) {
    float inv = g1[i] / sqrtf(v1[i] + EPS);
    bias1[i] = b1[i] - m1[i] * inv;
    float inv2 = g2[i] / sqrtf(v2[i] + EPS);
    s2[i] = inv2;
    t2[i] = b2[i] - m2[i] * inv2;
  }
  if (i < 128) {
    float inv = g3[i] / sqrtf(v3[i] + EPS);
    bias3[i] = b3[i] - m3[i] * inv;
  }
}

// ---------------------------------------------------------------- mask weights -> MFMA A-fragment layout (f16)
// wa[f][lane][j], f = (ph*25 + tap)*2 + ocf:
//   lane element j = W[oc = ocf*16 + (lane&15)][cm = ph*32 + (lane>>4)*8 + j][tap]
__global__ __launch_bounds__(256) void wtrans2_k(const float* __restrict__ we,
                                                 _Float16* __restrict__ wa) {
  int i = blockIdx.x * 256 + threadIdx.x;
  if (i >= 51200) return;
  int j = i & 7;
  int lane = (i >> 3) & 63;
  int f = i >> 9;             // 0..99
  int ocf = f & 1;
  int tap = (f >> 1) % 25;
  int ph = f / 50;
  int oc = ocf * 16 + (lane & 15);
  int cm = ph * 32 + (lane >> 4) * 8 + j;
  float v = (oc < 25) ? we[((size_t)oc * 64 + cm) * 25 + tap] : 0.f;
  wa[i] = (_Float16)v;
}

// ---------------------------------------------------------------- 1x1 conv via f16 MFMA
template <int IC, int NPF, int ACT, typename TI, typename TO>
__global__ __launch_bounds__(256) void gemm16_k(
    const TI* __restrict__ in, const _Float16* __restrict__ wh,
    const float* __restrict__ bias, TO* __restrict__ out, int npx) {
  constexpr int BPX = NPF * 64;
  constexpr int L2B = (BPX == 128) ? 7 : 6;
  __shared__ _Float16 xh[BPX][40];
  const int tid = threadIdx.x;
  const int lane = tid & 63;
  const int w = tid >> 6;
  const int l15 = lane & 15;
  const int g = lane >> 4;
  const int wpx = w * NPF * 16;
  const int p0 = blockIdx.x * BPX;
  const int oc0 = blockIdx.y * 64;
  const int b = blockIdx.z;
  const int OCT = gridDim.y * 64;
  const TI* inb = in + (size_t)b * IC * npx + p0;

  f32x4 acc[4][NPF];
#pragma unroll
  for (int fo = 0; fo < 4; ++fo)
#pragma unroll
    for (int pf = 0; pf < NPF; ++pf)
      acc[fo][pf] = (f32x4){0.f, 0.f, 0.f, 0.f};

  for (int kk = 0; kk < IC; kk += 32) {
    __syncthreads();
    half8 a[4];
#pragma unroll
    for (int fo = 0; fo < 4; ++fo)
      a[fo] = *(const half8*)&wh[(size_t)(oc0 + fo * 16 + l15) * IC + kk + g * 8];
#pragma unroll
    for (int i = 0; i < NPF * 2; ++i) {
      int slot = tid + 256 * i;
      int px = slot & (BPX - 1);
      int kq = slot >> L2B;
      const TI* src = inb + (size_t)(kk + kq * 4) * npx + px;
      half4 v = {(_Float16)src[0], (_Float16)src[npx],
                 (_Float16)src[2 * npx], (_Float16)src[3 * npx]};
      *(half4*)&xh[px][kq * 4] = v;
    }
    __syncthreads();
    half8 xb[NPF];
#pragma unroll
    for (int pf = 0; pf < NPF; ++pf)
      xb[pf] = *(const half8*)&xh[wpx + pf * 16 + l15][g * 8];
#pragma unroll
    for (int fo = 0; fo < 4; ++fo)
#pragma unroll
      for (int pf = 0; pf < NPF; ++pf)
        acc[fo][pf] = __builtin_amdgcn_mfma_f32_16x16x32_f16(
            a[fo], xb[pf], acc[fo][pf], 0, 0, 0);
  }

#pragma unroll
  for (int fo = 0; fo < 4; ++fo) {
#pragma unroll
    for (int r = 0; r < 4; ++r) {
      int oc = oc0 + fo * 16 + g * 4 + r;
      float bz = bias[oc];
#pragma unroll
      for (int pf = 0; pf < NPF; ++pf) {
        float v = acc[fo][pf][r] + bz;
        if (ACT) v = fminf(fmaxf(v, 0.f), 6.f);
        out[((size_t)b * OCT + oc) * npx + p0 + wpx + pf * 16 + l15] = (TO)v;
      }
    }
  }
}

// ---------------------------------------------------------------- mask conv 5x5 s2 via MFMA (v6)
// Block = (ho, b): 4 waves x 16 px = 64 px (56 valid). K = 64ch x 25taps,
// accumulated over 2 phases of 32 ch. logits written raw (bias in softmax).
__global__ __launch_bounds__(256) void mask_conv5_k(
    const _Float16* __restrict__ y, const _Float16* __restrict__ wa,
    float* __restrict__ lg) {
  __shared__ _Float16 ysh[32][5][136];  // row 272 B (16B-aligned); data at ci=8
  const int ho = blockIdx.x;  // 0..55
  const int b = blockIdx.y;   // 0..7
  const int tid = threadIdx.x;
  const int lane = tid & 63;
  const int w = tid >> 6;
  const int l15 = lane & 15;
  const int g = lane >> 4;
  const int wo = w * 16 + l15;
  const int woe = (wo < 56) ? wo : 55;
  const int ci0 = 2 * woe + 6;

  // zero pads: ci 0..7 and 120..135 for all [ch][ri]
  for (int i = tid; i < 640; i += 256) {
    int ch = i / 20; int rem = i - ch * 20; int ri = rem / 4; int q = rem & 3;
    *(uint*)&ysh[ch][ri][q * 2] = 0u;
  }
  for (int i = tid; i < 1280; i += 256) {
    int ch = i / 40; int rem = i - ch * 40; int ri = rem / 8; int q = rem & 7;
    *(uint*)&ysh[ch][ri][120 + q * 2] = 0u;
  }

  f32x4 acc[2] = {(f32x4){0.f, 0.f, 0.f, 0.f}, (f32x4){0.f, 0.f, 0.f, 0.f}};

  for (int ph = 0; ph < 2; ++ph) {
    __syncthreads();
    // stage 32 ch x 5 ri x 14 half8 (ci 8..119 <- wi 0..111); OOB rows -> 0
    for (int i = tid; i < 2240; i += 256) {
      int ch = i / 70;
      int rem = i - ch * 70;
      int ri = rem / 14;
      int j8 = rem - ri * 14;
      int hi = 2 * ho - 2 + ri;
      half8 v = {0, 0, 0, 0, 0, 0, 0, 0};
      if ((unsigned)hi < 112u)
        v = *(const half8*)&y[((size_t)(b * 64 + ph * 32 + ch) * 112 + hi) * 112 + j8 * 8];
      *(half8*)&ysh[ch][ri][8 + j8 * 8] = v;
    }
    __syncthreads();

    const _Float16* wap = wa + (size_t)ph * 25600;
#pragma unroll
    for (int di = 0; di < 5; ++di) {
      half2v pa[8], pb[8];
      _Float16 pc[8];
#pragma unroll
      for (int j = 0; j < 8; ++j) {
        pa[j] = *(const half2v*)&ysh[g * 8 + j][di][ci0];
        pb[j] = *(const half2v*)&ysh[g * 8 + j][di][ci0 + 2];
        pc[j] = ysh[g * 8 + j][di][ci0 + 4];
      }
#pragma unroll
      for (int dj = 0; dj < 5; ++dj) {
        half8 bf;
#pragma unroll
        for (int j = 0; j < 8; ++j)
          bf[j] = (dj == 0) ? pa[j][0]
                : (dj == 1) ? pa[j][1]
                : (dj == 2) ? pb[j][0]
                : (dj == 3) ? pb[j][1]
                            : pc[j];
        const int tap = di * 5 + dj;
        half8 a0 = *(const half8*)&wap[(tap * 2 + 0) * 512 + lane * 8];
        half8 a1 = *(const half8*)&wap[(tap * 2 + 1) * 512 + lane * 8];
        acc[0] = __builtin_amdgcn_mfma_f32_16x16x32_f16(a0, bf, acc[0], 0, 0, 0);
        acc[1] = __builtin_amdgcn_mfma_f32_16x16x32_f16(a1, bf, acc[1], 0, 0, 0);
      }
    }
  }

  if (wo < 56) {
#pragma unroll
    for (int ocf = 0; ocf < 2; ++ocf)
#pragma unroll
      for (int r = 0; r < 4; ++r) {
        int oc = ocf * 16 + g * 4 + r;
        if (oc < 25)
          lg[((size_t)b * 25 + oc) * 3136 + ho * 56 + wo] = acc[ocf][r];
      }
  }
}

// ---------------------------------------------------------------- softmax (logits + bias)
__global__ __launch_bounds__(256) void softmax3_k(
    const float* __restrict__ lg, const float* __restrict__ be,
    float* __restrict__ msk) {
  int idx = blockIdx.x * 256 + threadIdx.x;
  if (idx >= 8 * 3136) return;
  int b = idx / 3136, sp = idx - (idx / 3136) * 3136;
  float v[25];
  float mx = -1e30f;
#pragma unroll
  for (int k = 0; k < 25; ++k) {
    float s = lg[((size_t)b * 25 + k) * 3136 + sp] + be[k];
    v[k] = s;
    mx = fmaxf(mx, s);
  }
  float s = 0.f;
#pragma unroll
  for (int k = 0; k < 25; ++k) {
    v[k] = __expf(v[k] - mx);
    s += v[k];
  }
  float inv = 1.0f / s;
#pragma unroll
  for (int k = 0; k < 25; ++k)
    msk[((size_t)b * 25 + k) * 3136 + sp] = v[k] * inv;
}

// ---------------------------------------------------------------- carafe v4 (f16 h input, f16 h2 out)
__device__ __forceinline__ void stage_pair(float dst[2][19][120],
                                           const _Float16* __restrict__ hbase,
                                           int ho0, int tid) {
  for (int i = tid; i < 2 * 19 * 14; i += 512) {
    int ch = i / 266;
    int rem = i - ch * 266;
    int rr = rem / 14;
    int j8 = rem - rr * 14;
    int hi = 2 * ho0 - 2 + rr;
    float4 lo = {0.f, 0.f, 0.f, 0.f}, hi4 = {0.f, 0.f, 0.f, 0.f};
    if ((unsigned)hi < 112u) {
      half8 v = *(const half8*)&hbase[(size_t)ch * 12544 + hi * 112 + j8 * 8];
      lo = (float4){(float)v[0], (float)v[1], (float)v[2], (float)v[3]};
      hi4 = (float4){(float)v[4], (float)v[5], (float)v[6], (float)v[7]};
    }
    *(float4*)&dst[ch][rr][4 + j8 * 8] = lo;
    *(float4*)&dst[ch][rr][8 + j8 * 8] = hi4;
  }
}

__global__ __launch_bounds__(512) void carafe3_k(
    const _Float16* __restrict__ h, const float* __restrict__ msk,
    const float* __restrict__ s2, const float* __restrict__ t2,
    _Float16* __restrict__ h2) {
  __shared__ float ys[2][2][19][120];
  const int hx = blockIdx.x;   // 0..6
  const int b  = blockIdx.y;   // 0..7
  const int cz = blockIdx.z;   // 0..15
  const int ho0 = hx * 8;
  const int tid = threadIdx.x;
  const int r = tid / 56;
  const int c = tid - r * 56;
  const int c0 = cz * 24;

  for (int i = tid; i < 2 * 2 * 19 * 8; i += 512) {
    int bufi = i / 304;
    int rem = i - bufi * 304;
    int ch = rem / 152;
    int rem2 = rem - ch * 152;
    int rr = rem2 / 8;
    int p = rem2 - rr * 8;
    int col = (p < 4) ? p : (112 + p);
    ys[bufi][ch][rr][col] = 0.f;
  }

  float m[25];
  if (tid < 448) {
    const float* mp = msk + (size_t)b * 25 * 3136 + (ho0 + r) * 56 + c;
#pragma unroll
    for (int k = 0; k < 25; ++k) m[k] = mp[(size_t)k * 3136];
  }
  __syncthreads();

  stage_pair(ys[0], h + (size_t)(b * 384 + c0) * 12544, ho0, tid);
  __syncthreads();

#pragma unroll
  for (int p = 0; p < 12; ++p) {
    const int bf = p & 1;
    if (p + 1 < 12)
      stage_pair(ys[bf ^ 1], h + (size_t)(b * 384 + c0 + 2 * (p + 1)) * 12544,
                 ho0, tid);
    if (tid < 448) {
#pragma unroll
      for (int cl = 0; cl < 2; ++cl) {
        const int cc = c0 + 2 * p + cl;
        float acc = 0.f;
#pragma unroll
        for (int di = 0; di < 5; ++di) {
          const float* row = &ys[bf][cl][2 * r + di][2 * c + 2];
          float2 a01 = *(const float2*)&row[0];
          float2 a23 = *(const float2*)&row[2];
          float a4 = row[4];
          acc = fmaf(a01.x, m[di * 5 + 0], acc);
          acc = fmaf(a01.y, m[di * 5 + 1], acc);
          acc = fmaf(a23.x, m[di * 5 + 2], acc);
          acc = fmaf(a23.y, m[di * 5 + 3], acc);
          acc = fmaf(a4,    m[di * 5 + 4], acc);
        }
        float o = s2[cc] * acc + t2[cc];
        h2[((size_t)(b * 384 + cc) * 56 + ho0 + r) * 56 + c] =
            (_Float16)fminf(fmaxf(o, 0.f), 6.f);
      }
    }
    __syncthreads();
  }
}

// ---------------------------------------------------------------- launch
extern "C" void kernel_launch(void* const* d_in, const int* in_sizes, int n_in,
                              void* d_out, int out_size, void* d_ws, size_t ws_size,
                              hipStream_t stream) {
  const float* x  = (const float*)d_in[0];
  const float* w1 = (const float*)d_in[1];
  const float* g1 = (const float*)d_in[2];
  const float* b1 = (const float*)d_in[3];
  const float* m1 = (const float*)d_in[4];
  const float* v1 = (const float*)d_in[5];
  const float* wc = (const float*)d_in[6];
  const float* bc = (const float*)d_in[7];
  const float* we = (const float*)d_in[8];
  const float* be = (const float*)d_in[9];
  const float* g2 = (const float*)d_in[10];
  const float* b2 = (const float*)d_in[11];
  const float* m2 = (const float*)d_in[12];
  const float* v2 = (const float*)d_in[13];
  const float* w2 = (const float*)d_in[14];
  const float* g3 = (const float*)d_in[15];
  const float* b3 = (const float*)d_in[16];
  const float* m3 = (const float*)d_in[17];
  const float* v3 = (const float*)d_in[18];
  float* out = (float*)d_out;

  // workspace layout
  _Float16* hq  = (_Float16*)d_ws;          // 38,535,168 halves
  _Float16* yq  = hq + 38535168;            //  6,422,528 halves
  _Float16* h2q = yq + 6422528;             //  9,633,792 halves
  float* lg     = (float*)(h2q + 9633792);  //    627,200 floats (raw logits)
  float* mskf   = lg + 627200;              //    627,200 floats
  float* bias1  = mskf + 627200;            // 384
  float* bias3  = bias1 + 384;              // 128
  float* s2     = bias3 + 128;              // 384
  float* t2     = s2 + 384;                 // 384
  _Float16* w1h = (_Float16*)(t2 + 384);    // 24576 halves
  _Float16* wch = w1h + 24576;              // 24576 halves
  _Float16* w2h = wch + 24576;              // 49152 halves
  _Float16* wa  = w2h + 49152;              // 51200 halves (MFMA A-frags)

  fold_k<<<192, 256, 0, stream>>>(w1, g1, b1, m1, v1, wc, g2, b2, m2, v2,
                                  w2, g3, b3, m3, v3,
                                  w1h, bias1, wch, w2h, bias3, s2, t2);
  wtrans2_k<<<200, 256, 0, stream>>>(we, wa);

  // stage 1: h = relu6(bn1(conv1x1(x, w1)))  [fp32 in, f16 out]
  gemm16_k<64, 2, 1, float, _Float16>
      <<<dim3(98, 6, 8), 256, 0, stream>>>(x, w1h, bias1, hq, 12544);

  // compressor: y = conv1x1(h, wc) + bc  [f16 in, f16 out]
  gemm16_k<384, 2, 0, _Float16, _Float16>
      <<<dim3(98, 1, 8), 256, 0, stream>>>(hq, wch, bc, yq, 12544);

  // mask conv via MFMA (full K reduction, raw logits) + softmax(+bias)
  mask_conv5_k<<<dim3(56, 8), 256, 0, stream>>>(yq, wa, lg);
  softmax3_k<<<98, 256, 0, stream>>>(lg, be, mskf);

  // carafe + bn2 + relu6  [f16 in/out]
  carafe3_k<<<dim3(7, 8, 16), 512, 0, stream>>>(hq, mskf, s2, t2, h2q);

  // final: out = bn3(conv1x1(h2, w2))  [f16 in, fp32 out]
  gemm16_k<384, 1, 0, _Float16, float>
      <<<dim3(49, 2, 8), 256, 0, stream>>>(h2q, w2h, bias3, out, 3136);
}

// Round 9
// 162.466 us; speedup vs baseline: 7.3945x; 1.0044x over previous
//
#include <hip/hip_runtime.h>
#include <hip/hip_bf16.h>
#include <type_traits>

#define EPS 1e-5f

typedef _Float16 half8 __attribute__((ext_vector_type(8)));
typedef _Float16 half4 __attribute__((ext_vector_type(4)));
typedef _Float16 half2v __attribute__((ext_vector_type(2)));
typedef float f32x4 __attribute__((ext_vector_type(4)));

// ---------------------------------------------------------------- fold bn (+ f16 weight conversion)
__global__ __launch_bounds__(256) void fold_k(
    const float* __restrict__ w1, const float* __restrict__ g1, const float* __restrict__ b1,
    const float* __restrict__ m1, const float* __restrict__ v1,
    const float* __restrict__ wc,
    const float* __restrict__ g2, const float* __restrict__ b2,
    const float* __restrict__ m2, const float* __restrict__ v2,
    const float* __restrict__ w2, const float* __restrict__ g3, const float* __restrict__ b3,
    const float* __restrict__ m3, const float* __restrict__ v3,
    _Float16* __restrict__ w1h, float* __restrict__ bias1,
    _Float16* __restrict__ wch,
    _Float16* __restrict__ w2h, float* __restrict__ bias3,
    float* __restrict__ s2, float* __restrict__ t2) {
  int i = blockIdx.x * 256 + threadIdx.x;
  if (i < 384 * 64) {
    int o = i >> 6;
    float inv = g1[o] / sqrtf(v1[o] + EPS);
    w1h[i] = (_Float16)(w1[i] * inv);
  }
  if (i < 64 * 384) wch[i] = (_Float16)wc[i];
  if (i < 128 * 384) {
    int o = i / 384;
    float inv = g3[o] / sqrtf(v3[o] + EPS);
    w2h[i] = (_Float16)(w2[i] * inv);
  }
  if (i < 384) {
    float inv = g1[i] / sqrtf(v1[i] + EPS);
    bias1[i] = b1[i] - m1[i] * inv;
    float inv2 = g2[i] / sqrtf(v2[i] + EPS);
    s2[i] = inv2;
    t2[i] = b2[i] - m2[i] * inv2;
  }
  if (i < 128) {
    float inv = g3[i] / sqrtf(v3[i] + EPS);
    bias3[i] = b3[i] - m3[i] * inv;
  }
}

// ---------------------------------------------------------------- mask weights -> MFMA A-fragment layout (f16)
__global__ __launch_bounds__(256) void wtrans2_k(const float* __restrict__ we,
                                                 _Float16* __restrict__ wa) {
  int i = blockIdx.x * 256 + threadIdx.x;
  if (i >= 51200) return;
  int j = i & 7;
  int lane = (i >> 3) & 63;
  int f = i >> 9;             // 0..99
  int ocf = f & 1;
  int tap = (f >> 1) % 25;
  int ph = f / 50;
  int oc = ocf * 16 + (lane & 15);
  int cm = ph * 32 + (lane >> 4) * 8 + j;
  float v = (oc < 25) ? we[((size_t)oc * 64 + cm) * 25 + tap] : 0.f;
  wa[i] = (_Float16)v;
}

// ---------------------------------------------------------------- 1x1 conv via f16 MFMA (v3)
// grid = (OC/64, npx/BPX, B): oc-major so same-x blocks are consecutive (L2 reuse).
// Epilogue: per-wave LDS transpose -> 16B vectorized stores.
template <int IC, int NPF, int ACT, typename TI, typename TO>
__global__ __launch_bounds__(256) void gemm16_k(
    const TI* __restrict__ in, const _Float16* __restrict__ wh,
    const float* __restrict__ bias, TO* __restrict__ out, int npx) {
  constexpr int BPX = NPF * 64;
  constexpr int L2B = (BPX == 128) ? 7 : 6;
  constexpr int PAD = 16 / sizeof(TO);     // pad to keep rows 16B-aligned
  constexpr int CH = 16 / sizeof(TO);      // elems per 16B chunk
  constexpr int SPAN = NPF * 16;           // px per wave
  constexpr int LPO = SPAN / CH;           // lanes per oc row
  constexpr int OCPI = 64 / LPO;           // oc rows per store inst
  using vec16 = std::conditional_t<std::is_same_v<TO, _Float16>, half8, float4>;

  __shared__ _Float16 xh[BPX][40];
  __shared__ TO oT[64][BPX + PAD];

  const int tid = threadIdx.x;
  const int lane = tid & 63;
  const int w = tid >> 6;
  const int l15 = lane & 15;
  const int g = lane >> 4;
  const int wpx = w * SPAN;
  const int oc0 = blockIdx.x * 64;
  const int p0 = blockIdx.y * BPX;
  const int b = blockIdx.z;
  const int OCT = gridDim.x * 64;
  const TI* inb = in + (size_t)b * IC * npx + p0;

  f32x4 acc[4][NPF];
#pragma unroll
  for (int fo = 0; fo < 4; ++fo)
#pragma unroll
    for (int pf = 0; pf < NPF; ++pf)
      acc[fo][pf] = (f32x4){0.f, 0.f, 0.f, 0.f};

  for (int kk = 0; kk < IC; kk += 32) {
    __syncthreads();
    half8 a[4];
#pragma unroll
    for (int fo = 0; fo < 4; ++fo)
      a[fo] = *(const half8*)&wh[(size_t)(oc0 + fo * 16 + l15) * IC + kk + g * 8];
#pragma unroll
    for (int i = 0; i < NPF * 2; ++i) {
      int slot = tid + 256 * i;
      int px = slot & (BPX - 1);
      int kq = slot >> L2B;
      const TI* src = inb + (size_t)(kk + kq * 4) * npx + px;
      half4 v = {(_Float16)src[0], (_Float16)src[npx],
                 (_Float16)src[2 * npx], (_Float16)src[3 * npx]};
      *(half4*)&xh[px][kq * 4] = v;
    }
    __syncthreads();
    half8 xb[NPF];
#pragma unroll
    for (int pf = 0; pf < NPF; ++pf)
      xb[pf] = *(const half8*)&xh[wpx + pf * 16 + l15][g * 8];
#pragma unroll
    for (int fo = 0; fo < 4; ++fo)
#pragma unroll
      for (int pf = 0; pf < NPF; ++pf)
        acc[fo][pf] = __builtin_amdgcn_mfma_f32_16x16x32_f16(
            a[fo], xb[pf], acc[fo][pf], 0, 0, 0);
  }

  // epilogue: bias/act -> per-wave LDS transpose (wave-local, no barrier)
#pragma unroll
  for (int fo = 0; fo < 4; ++fo) {
#pragma unroll
    for (int r = 0; r < 4; ++r) {
      float bz = bias[oc0 + fo * 16 + g * 4 + r];
#pragma unroll
      for (int pf = 0; pf < NPF; ++pf) {
        float v = acc[fo][pf][r] + bz;
        if (ACT) v = fminf(fmaxf(v, 0.f), 6.f);
        oT[fo * 16 + g * 4 + r][wpx + pf * 16 + l15] = (TO)v;
      }
    }
  }
  // vectorized stores: 16B per lane
#pragma unroll
  for (int i = 0; i < LPO; ++i) {
    int oc = i * OCPI + lane / LPO;
    int pxo = (lane % LPO) * CH;
    vec16 v = *(const vec16*)&oT[oc][wpx + pxo];
    *(vec16*)&out[((size_t)b * OCT + oc0 + oc) * npx + p0 + wpx + pxo] = v;
  }
}

// ---------------------------------------------------------------- mask conv 5x5 s2 via MFMA (v6)
__global__ __launch_bounds__(256) void mask_conv5_k(
    const _Float16* __restrict__ y, const _Float16* __restrict__ wa,
    float* __restrict__ lg) {
  __shared__ _Float16 ysh[32][5][136];
  const int ho = blockIdx.x;
  const int b = blockIdx.y;
  const int tid = threadIdx.x;
  const int lane = tid & 63;
  const int w = tid >> 6;
  const int l15 = lane & 15;
  const int g = lane >> 4;
  const int wo = w * 16 + l15;
  const int woe = (wo < 56) ? wo : 55;
  const int ci0 = 2 * woe + 6;

  for (int i = tid; i < 640; i += 256) {
    int ch = i / 20; int rem = i - ch * 20; int ri = rem / 4; int q = rem & 3;
    *(uint*)&ysh[ch][ri][q * 2] = 0u;
  }
  for (int i = tid; i < 1280; i += 256) {
    int ch = i / 40; int rem = i - ch * 40; int ri = rem / 8; int q = rem & 7;
    *(uint*)&ysh[ch][ri][120 + q * 2] = 0u;
  }

  f32x4 acc[2] = {(f32x4){0.f, 0.f, 0.f, 0.f}, (f32x4){0.f, 0.f, 0.f, 0.f}};

  for (int ph = 0; ph < 2; ++ph) {
    __syncthreads();
    for (int i = tid; i < 2240; i += 256) {
      int ch = i / 70;
      int rem = i - ch * 70;
      int ri = rem / 14;
      int j8 = rem - ri * 14;
      int hi = 2 * ho - 2 + ri;
      half8 v = {0, 0, 0, 0, 0, 0, 0, 0};
      if ((unsigned)hi < 112u)
        v = *(const half8*)&y[((size_t)(b * 64 + ph * 32 + ch) * 112 + hi) * 112 + j8 * 8];
      *(half8*)&ysh[ch][ri][8 + j8 * 8] = v;
    }
    __syncthreads();

    const _Float16* wap = wa + (size_t)ph * 25600;
#pragma unroll
    for (int di = 0; di < 5; ++di) {
      half2v pa[8], pb[8];
      _Float16 pc[8];
#pragma unroll
      for (int j = 0; j < 8; ++j) {
        pa[j] = *(const half2v*)&ysh[g * 8 + j][di][ci0];
        pb[j] = *(const half2v*)&ysh[g * 8 + j][di][ci0 + 2];
        pc[j] = ysh[g * 8 + j][di][ci0 + 4];
      }
#pragma unroll
      for (int dj = 0; dj < 5; ++dj) {
        half8 bf;
#pragma unroll
        for (int j = 0; j < 8; ++j)
          bf[j] = (dj == 0) ? pa[j][0]
                : (dj == 1) ? pa[j][1]
                : (dj == 2) ? pb[j][0]
                : (dj == 3) ? pb[j][1]
                            : pc[j];
        const int tap = di * 5 + dj;
        half8 a0 = *(const half8*)&wap[(tap * 2 + 0) * 512 + lane * 8];
        half8 a1 = *(const half8*)&wap[(tap * 2 + 1) * 512 + lane * 8];
        acc[0] = __builtin_amdgcn_mfma_f32_16x16x32_f16(a0, bf, acc[0], 0, 0, 0);
        acc[1] = __builtin_amdgcn_mfma_f32_16x16x32_f16(a1, bf, acc[1], 0, 0, 0);
      }
    }
  }

  if (wo < 56) {
#pragma unroll
    for (int ocf = 0; ocf < 2; ++ocf)
#pragma unroll
      for (int r = 0; r < 4; ++r) {
        int oc = ocf * 16 + g * 4 + r;
        if (oc < 25)
          lg[((size_t)b * 25 + oc) * 3136 + ho * 56 + wo] = acc[ocf][r];
      }
  }
}

// ---------------------------------------------------------------- softmax (logits + bias)
__global__ __launch_bounds__(256) void softmax3_k(
    const float* __restrict__ lg, const float* __restrict__ be,
    float* __restrict__ msk) {
  int idx = blockIdx.x * 256 + threadIdx.x;
  if (idx >= 8 * 3136) return;
  int b = idx / 3136, sp = idx - (idx / 3136) * 3136;
  float v[25];
  float mx = -1e30f;
#pragma unroll
  for (int k = 0; k < 25; ++k) {
    float s = lg[((size_t)b * 25 + k) * 3136 + sp] + be[k];
    v[k] = s;
    mx = fmaxf(mx, s);
  }
  float s = 0.f;
#pragma unroll
  for (int k = 0; k < 25; ++k) {
    v[k] = __expf(v[k] - mx);
    s += v[k];
  }
  float inv = 1.0f / s;
#pragma unroll
  for (int k = 0; k < 25; ++k)
    msk[((size_t)b * 25 + k) * 3136 + sp] = v[k] * inv;
}

// ---------------------------------------------------------------- carafe v4 (f16 h input, f16 h2 out)
__device__ __forceinline__ void stage_pair(float dst[2][19][120],
                                           const _Float16* __restrict__ hbase,
                                           int ho0, int tid) {
  for (int i = tid; i < 2 * 19 * 14; i += 512) {
    int ch = i / 266;
    int rem = i - ch * 266;
    int rr = rem / 14;
    int j8 = rem - rr * 14;
    int hi = 2 * ho0 - 2 + rr;
    float4 lo = {0.f, 0.f, 0.f, 0.f}, hi4 = {0.f, 0.f, 0.f, 0.f};
    if ((unsigned)hi < 112u) {
      half8 v = *(const half8*)&hbase[(size_t)ch * 12544 + hi * 112 + j8 * 8];
      lo = (float4){(float)v[0], (float)v[1], (float)v[2], (float)v[3]};
      hi4 = (float4){(float)v[4], (float)v[5], (float)v[6], (float)v[7]};
    }
    *(float4*)&dst[ch][rr][4 + j8 * 8] = lo;
    *(float4*)&dst[ch][rr][8 + j8 * 8] = hi4;
  }
}

__global__ __launch_bounds__(512) void carafe3_k(
    const _Float16* __restrict__ h, const float* __restrict__ msk,
    const float* __restrict__ s2, const float* __restrict__ t2,
    _Float16* __restrict__ h2) {
  __shared__ float ys[2][2][19][120];
  const int hx = blockIdx.x;   // 0..6
  const int b  = blockIdx.y;   // 0..7
  const int cz = blockIdx.z;   // 0..15
  const int ho0 = hx * 8;
  const int tid = threadIdx.x;
  const int r = tid / 56;
  const int c = tid - r * 56;
  const int c0 = cz * 24;

  for (int i = tid; i < 2 * 2 * 19 * 8; i += 512) {
    int bufi = i / 304;
    int rem = i - bufi * 304;
    int ch = rem / 152;
    int rem2 = rem - ch * 152;
    int rr = rem2 / 8;
    int p = rem2 - rr * 8;
    int col = (p < 4) ? p : (112 + p);
    ys[bufi][ch][rr][col] = 0.f;
  }

  float m[25];
  if (tid < 448) {
    const float* mp = msk + (size_t)b * 25 * 3136 + (ho0 + r) * 56 + c;
#pragma unroll
    for (int k = 0; k < 25; ++k) m[k] = mp[(size_t)k * 3136];
  }
  __syncthreads();

  stage_pair(ys[0], h + (size_t)(b * 384 + c0) * 12544, ho0, tid);
  __syncthreads();

#pragma unroll
  for (int p = 0; p < 12; ++p) {
    const int bf = p & 1;
    if (p + 1 < 12)
      stage_pair(ys[bf ^ 1], h + (size_t)(b * 384 + c0 + 2 * (p + 1)) * 12544,
                 ho0, tid);
    if (tid < 448) {
#pragma unroll
      for (int cl = 0; cl < 2; ++cl) {
        const int cc = c0 + 2 * p + cl;
        float acc = 0.f;
#pragma unroll
        for (int di = 0; di < 5; ++di) {
          const float* row = &ys[bf][cl][2 * r + di][2 * c + 2];
          float2 a01 = *(const float2*)&row[0];
          float2 a23 = *(const float2*)&row[2];
          float a4 = row[4];
          acc = fmaf(a01.x, m[di * 5 + 0], acc);
          acc = fmaf(a01.y, m[di * 5 + 1], acc);
          acc = fmaf(a23.x, m[di * 5 + 2], acc);
          acc = fmaf(a23.y, m[di * 5 + 3], acc);
          acc = fmaf(a4,    m[di * 5 + 4], acc);
        }
        float o = s2[cc] * acc + t2[cc];
        h2[((size_t)(b * 384 + cc) * 56 + ho0 + r) * 56 + c] =
            (_Float16)fminf(fmaxf(o, 0.f), 6.f);
      }
    }
    __syncthreads();
  }
}

// ---------------------------------------------------------------- launch
extern "C" void kernel_launch(void* const* d_in, const int* in_sizes, int n_in,
                              void* d_out, int out_size, void* d_ws, size_t ws_size,
                              hipStream_t stream) {
  const float* x  = (const float*)d_in[0];
  const float* w1 = (const float*)d_in[1];
  const float* g1 = (const float*)d_in[2];
  const float* b1 = (const float*)d_in[3];
  const float* m1 = (const float*)d_in[4];
  const float* v1 = (const float*)d_in[5];
  const float* wc = (const float*)d_in[6];
  const float* bc = (const float*)d_in[7];
  const float* we = (const float*)d_in[8];
  const float* be = (const float*)d_in[9];
  const float* g2 = (const float*)d_in[10];
  const float* b2 = (const float*)d_in[11];
  const float* m2 = (const float*)d_in[12];
  const float* v2 = (const float*)d_in[13];
  const float* w2 = (const float*)d_in[14];
  const float* g3 = (const float*)d_in[15];
  const float* b3 = (const float*)d_in[16];
  const float* m3 = (const float*)d_in[17];
  const float* v3 = (const float*)d_in[18];
  float* out = (float*)d_out;

  // workspace layout
  _Float16* hq  = (_Float16*)d_ws;          // 38,535,168 halves
  _Float16* yq  = hq + 38535168;            //  6,422,528 halves
  _Float16* h2q = yq + 6422528;             //  9,633,792 halves
  float* lg     = (float*)(h2q + 9633792);  //    627,200 floats (raw logits)
  float* mskf   = lg + 627200;              //    627,200 floats
  float* bias1  = mskf + 627200;            // 384
  float* bias3  = bias1 + 384;              // 128
  float* s2     = bias3 + 128;              // 384
  float* t2     = s2 + 384;                 // 384
  _Float16* w1h = (_Float16*)(t2 + 384);    // 24576 halves
  _Float16* wch = w1h + 24576;              // 24576 halves
  _Float16* w2h = wch + 24576;              // 49152 halves
  _Float16* wa  = w2h + 49152;              // 51200 halves (MFMA A-frags)

  fold_k<<<192, 256, 0, stream>>>(w1, g1, b1, m1, v1, wc, g2, b2, m2, v2,
                                  w2, g3, b3, m3, v3,
                                  w1h, bias1, wch, w2h, bias3, s2, t2);
  wtrans2_k<<<200, 256, 0, stream>>>(we, wa);

  // stage 1: h = relu6(bn1(conv1x1(x, w1)))  [fp32 in, f16 out]
  gemm16_k<64, 2, 1, float, _Float16>
      <<<dim3(6, 98, 8), 256, 0, stream>>>(x, w1h, bias1, hq, 12544);

  // compressor: y = conv1x1(h, wc) + bc  [f16 in, f16 out]
  gemm16_k<384, 2, 0, _Float16, _Float16>
      <<<dim3(1, 98, 8), 256, 0, stream>>>(hq, wch, bc, yq, 12544);

  // mask conv via MFMA + softmax(+bias)
  mask_conv5_k<<<dim3(56, 8), 256, 0, stream>>>(yq, wa, lg);
  softmax3_k<<<98, 256, 0, stream>>>(lg, be, mskf);

  // carafe + bn2 + relu6  [f16 in/out]
  carafe3_k<<<dim3(7, 8, 16), 512, 0, stream>>>(hq, mskf, s2, t2, h2q);

  // final: out = bn3(conv1x1(h2, w2))  [f16 in, fp32 out]
  gemm16_k<384, 1, 0, _Float16, float>
      <<<dim3(2, 49, 8), 256, 0, stream>>>(h2q, w2h, bias3, out, 3136);
}